// Round 1
// baseline (302.966 us; speedup 1.0000x reference)
//
#include <hip/hip_runtime.h>

typedef unsigned short u16;
typedef unsigned char u8;
typedef short s16x8 __attribute__((ext_vector_type(8)));
typedef unsigned short u16x4 __attribute__((ext_vector_type(4)));
typedef float f32x4 __attribute__((ext_vector_type(4)));
typedef int i32x4 __attribute__((ext_vector_type(4)));
typedef int i32x8 __attribute__((ext_vector_type(8)));

#define AS1 __attribute__((address_space(1)))
#define AS3 __attribute__((address_space(3)))

// async global->LDS, 16B per lane; LDS dest = wave-uniform base + lane*16
__device__ __forceinline__ void g2l16(const void* g, void* l) {
  __builtin_amdgcn_global_load_lds((const AS1 void*)g, (AS3 void*)l, 16, 0, 0);
}

__device__ __forceinline__ float b2f(u16 u) {
  union { unsigned int i; float f; } x; x.i = ((unsigned int)u) << 16; return x.f;
}
__device__ __forceinline__ u16 f2b(float f) {  // round-to-nearest-even
  unsigned int u = __builtin_bit_cast(unsigned int, f);
  return (u16)((u + 0x7fffu + ((u >> 16) & 1u)) >> 16);
}
__device__ __forceinline__ u8 f2e4m3(float v) {
  int p = __builtin_amdgcn_cvt_pk_fp8_f32(v, 0.f, 0, false);
  return (u8)(p & 0xff);
}
__device__ __forceinline__ float sigm(float x) { return 1.f / (1.f + __expf(-x)); }
__device__ __forceinline__ float tanh_f(float x) { return 2.f / (1.f + __expf(-2.f * x)) - 1.f; }

// dims: T=48 N=4096 F_IN=H1=F_OUT=64; TH = 3072

// ---------------- kpre: adj->fp8 + weight prep + k1 (XHT), one launch ----------------
// blocks [0,4096): adj fp32->fp8 e4m3 scaled x4096 (coalesced)
// blocks [4096,4144): wct;  [4144,4147): lbt;  [4147,5683): XHT tiles
__global__ __launch_bounds__(256) void kpre(
    const float* __restrict__ a, u8* __restrict__ ab,
    const float* __restrict__ fcw, const float* __restrict__ fcb,
    const float* __restrict__ x, u8* __restrict__ xht,
    const float* __restrict__ Wz, const float* __restrict__ Wr, const float* __restrict__ Wh,
    const float* __restrict__ Lz, const float* __restrict__ Lr, const float* __restrict__ Lh,
    u16* __restrict__ wct, u16* __restrict__ lbt) {
  int b = blockIdx.x, tid = threadIdx.x;
  if (b < 4096) {
    size_t idx = (size_t)b * 256 + tid;   // lane-contiguous float4 index
    const float4* src = (const float4*)a;
    unsigned int* dst = (unsigned int*)ab;
#pragma unroll
    for (int k = 0; k < 4; ++k) {
      float4 v = src[idx + (size_t)k * 1048576];
      unsigned int p = __builtin_amdgcn_cvt_pk_fp8_f32(v.x * 4096.f, v.y * 4096.f, 0, false);
      p = __builtin_amdgcn_cvt_pk_fp8_f32(v.z * 4096.f, v.w * 4096.f, p, true);
      dst[idx + (size_t)k * 1048576] = p;
    }
    return;
  }
  if (b < 4144) {
    int idx = (b - 4096) * 256 + tid;  // 0..12287
    int c_cat = idx >> 6, hh = idx & 63;
    int g = c_cat >> 6, c = c_cat & 63;
    const float* W = (g == 0) ? Wz : (g == 1) ? Wr : Wh;
    const float* L = (g == 0) ? Lz : (g == 1) ? Lr : Lh;
    float acc = 0.f;
    for (int m = 0; m < 64; ++m) acc += W[hh * 64 + m] * L[m * 64 + c];
    wct[c_cat * 64 + hh] = f2b(acc);
    return;
  }
  if (b < 4147) {
    int g = b - 4144;
    const float* L = (g == 0) ? Lz : (g == 1) ? Lr : Lh;
    for (int i = 0; i < 16; ++i) {
      int idx = tid * 16 + i; int c = idx >> 6, hh = idx & 63;
      lbt[g * 4096 + c * 64 + hh] = f2b(L[(64 + hh) * 64 + c]);
    }
    return;
  }
  // ---- XHT part: kb in [0,1536): t = kb>>5, n0 = (kb&31)*128 ----
  int kb = b - 4147;
  int t = kb >> 5, n0 = (kb & 31) * 128;
  __shared__ __align__(16) u16 xs[128 * 72];   // padded: 2-way banks
  __shared__ __align__(16) u16 fw[64 * 72];
  __shared__ __align__(16) u8 xh8[64 * 128];   // [h][node]
  __shared__ float fb[64];
  int w = tid >> 6, l = tid & 63;
#pragma unroll
  for (int i = 0; i < 16; ++i) {       // fw[h][f] = fc_w[f][h], coalesced fp32 reads
    int idx = tid + i * 256;
    int h = idx & 63, f = idx >> 6;
    fw[h * 72 + f] = f2b(fcw[f * 64 + h]);
  }
  const float4* xg = (const float4*)(x + ((size_t)t * 4096 + n0) * 64);
#pragma unroll
  for (int i = 0; i < 8; ++i) {
    int f = tid + i * 256;             // lane-contiguous float4 index
    float4 v = xg[f];
    u16x4 p; p[0] = f2b(v.x); p[1] = f2b(v.y); p[2] = f2b(v.z); p[3] = f2b(v.w);
    *(u16x4*)&xs[(f >> 4) * 72 + (f & 15) * 4] = p;
  }
  if (tid < 64) fb[tid] = fcb[tid];
  __syncthreads();

  int lm = l & 15, q = l >> 4;
  f32x4 acc[4][2];
#pragma unroll
  for (int i = 0; i < 4; ++i)
#pragma unroll
    for (int j = 0; j < 2; ++j)
#pragma unroll
      for (int r = 0; r < 4; ++r) acc[i][j][r] = 0.f;
#pragma unroll
  for (int s = 0; s < 2; ++s) {
    s16x8 af[4], bf[2];
#pragma unroll
    for (int i = 0; i < 4; ++i) af[i] = *(const s16x8*)&fw[(16 * i + lm) * 72 + 32 * s + q * 8];
#pragma unroll
    for (int j = 0; j < 2; ++j) bf[j] = *(const s16x8*)&xs[(32 * w + 16 * j + lm) * 72 + 32 * s + q * 8];
#pragma unroll
    for (int i = 0; i < 4; ++i)
#pragma unroll
      for (int j = 0; j < 2; ++j)
        acc[i][j] = __builtin_amdgcn_mfma_f32_16x16x32_bf16(af[i], bf[j], acc[i][j], 0, 0, 0);
  }
#pragma unroll
  for (int i = 0; i < 4; ++i)
#pragma unroll
    for (int j = 0; j < 2; ++j) {
      int node = 32 * w + 16 * j + lm;
      int h0 = 16 * i + q * 4;
#pragma unroll
      for (int r = 0; r < 4; ++r) {
        float v = acc[i][j][r] + fb[h0 + r];
        xh8[(h0 + r) * 128 + node] = f2e4m3(v > 0.f ? v : 0.f);
      }
    }
  __syncthreads();
  {
    int h = tid >> 2, seg = tid & 3;   // 32 bytes per thread
    u8* dst = xht + (size_t)(t * 64 + h) * 4096 + n0 + seg * 32;
    const u8* src = &xh8[h * 128 + seg * 32];
    *(i32x4*)dst = *(const i32x4*)src;
    *(i32x4*)(dst + 16) = *(const i32x4*)(src + 16);
  }
}

// ---------------- k2: M = adj8 @ XH8, MX fp8 K=128 ----------------
// 256x192 tile, 512 threads (8 waves as 4x2, wave tile 64x96).
// A operand: direct global->VGPR (L1/L2-resident panel, no LDS round trip).
// B operand: LDS double-buffered (2 x 24KB), rotation swizzle, prefetch-
// before-compute so the stage's vmcnt drain lands after ~1.7k cycles of MFMA.
__global__ __launch_bounds__(512, 2) void k2(
    const u8* __restrict__ A, const u8* __restrict__ B, u16* __restrict__ M) {
  __shared__ __align__(16) u8 sh[49152];        // 2 x (192 rows x 128B)
  int tid = threadIdx.x, w = tid >> 6, l = tid & 63;
  int nt = blockIdx.x, mt = blockIdx.y;
  const u8* Ab = A + (size_t)mt * 256 * 4096;
  const u8* Bb = B + (size_t)nt * 192 * 4096;
  int lm = l & 15, q = l >> 4;
  int wm = w >> 1, wn = w & 1;                  // wave tile: rows 64*wm, cols 96*wn
  int srow = l >> 3, scol = l & 7;
  f32x4 acc[4][6];
#pragma unroll
  for (int i = 0; i < 4; ++i)
#pragma unroll
    for (int j = 0; j < 6; ++j)
#pragma unroll
      for (int r = 0; r < 4; ++r) acc[i][j][r] = 0.f;

#define STAGE_B(bsel, kk)                                                     \
  do {                                                                        \
    _Pragma("unroll") for (int j = 0; j < 3; ++j) {                           \
      int r0 = 24 * w + 8 * j;                                                \
      int row = r0 + srow;                                                    \
      int c = (scol - row) & 7;                                               \
      g2l16(Bb + (size_t)row * 4096 + (kk) + c * 16,                          \
            sh + (bsel) * 24576 + r0 * 128);                                  \
    }                                                                         \
  } while (0)

  STAGE_B(0, 0);
  __syncthreads();                     // buf0 ready

  for (int it = 0; it < 32; ++it) {
    int k0b = it * 128;
    int cur = it & 1;
    // A fragments: direct global loads FIRST (vmcnt retires in issue order,
    // so the MFMA's waitcnt leaves the later-stage g2l16s in flight).
    i32x8 a8[4];
#pragma unroll
    for (int i = 0; i < 4; ++i) {
      int ra = 64 * wm + 16 * i + lm;
      a8[i] = *(const i32x8*)(Ab + (size_t)ra * 4096 + k0b + q * 32);
    }
    if (it < 31) STAGE_B(cur ^ 1, k0b + 128);   // prefetch next K-tile of B
    const u8* Bs = sh + cur * 24576;
#pragma unroll
    for (int j = 0; j < 6; ++j) {
      int rb = 96 * wn + 16 * j + lm;
      int q0 = (2 * q + rb) & 7, q1 = (2 * q + 1 + rb) & 7;
      i32x4 lo = *(const i32x4*)&Bs[rb * 128 + q0 * 16];
      i32x4 hi = *(const i32x4*)&Bs[rb * 128 + q1 * 16];
      i32x8 b8 = __builtin_shufflevector(lo, hi, 0, 1, 2, 3, 4, 5, 6, 7);
#pragma unroll
      for (int i = 0; i < 4; ++i)
        acc[i][j] = __builtin_amdgcn_mfma_scale_f32_16x16x128_f8f6f4(
            a8[i], b8, acc[i][j], 0, 0, 0, 127, 0, 127);  // fmt=fp8, scale=2^0
    }
    __syncthreads();                   // next buffer staged; this buffer free
  }
#undef STAGE_B

  // epilogue: 4-pass transpose through LDS. tb = [64][200] u16 (25.6KB)
  u16* tb = (u16*)sh;
  const float sc = 1.f / 4096.f;
#pragma unroll
  for (int p = 0; p < 4; ++p) {
    if (p) __syncthreads();            // prior pass's LDS reads done before overwrite
    if (wm == p) {
#pragma unroll
      for (int i = 0; i < 4; ++i)
#pragma unroll
        for (int j = 0; j < 6; ++j)
#pragma unroll
          for (int r = 0; r < 4; ++r)
            tb[(16 * i + 4 * q + r) * 200 + 96 * wn + 16 * j + lm] = f2b(acc[i][j][r] * sc);
    }
    __syncthreads();
    int row = tid >> 3, seg = tid & 7;   // 64 rows x 384B; 48B (24 u16) per thread
    u16* dst = M + (size_t)(mt * 256 + p * 64 + row) * 3072 + nt * 192 + seg * 24;
    const u16* src = &tb[row * 200 + seg * 24];
#pragma unroll
    for (int v = 0; v < 3; ++v)
      *(i32x4*)(dst + 8 * v) = *(const i32x4*)(src + 8 * v);
  }
}

// ---------------- k3: GRU scan; weights in regs, 2 barriers/step, split acc chains ----------------
__global__ __launch_bounds__(256) void k3(
    const u16* __restrict__ M, const u16* __restrict__ wct, const u16* __restrict__ lbt,
    const float* __restrict__ bz, const float* __restrict__ br, const float* __restrict__ bh,
    float* __restrict__ out) {
  __shared__ __align__(16) u16 hhi[16 * 72], hlo[16 * 72];
  __shared__ __align__(16) u16 rhi[16 * 72], rlo[16 * 72];
  int tid = threadIdx.x, w = tid >> 6, l = tid & 63;
  int nb0 = blockIdx.x * 16;
  int lm = l & 15, q = l >> 4;
  int cb = 16 * w + q * 4;
  s16x8 afw[3][2], afl[3][2];
#pragma unroll
  for (int g = 0; g < 3; ++g)
#pragma unroll
    for (int s = 0; s < 2; ++s) {
      afw[g][s] = *(const s16x8*)&wct[(size_t)(g * 64 + 16 * w + lm) * 64 + 32 * s + q * 8];
      afl[g][s] = *(const s16x8*)&lbt[(size_t)(g * 64 + 16 * w + lm) * 64 + 32 * s + q * 8];
    }
  for (int i = tid; i < 16 * 72; i += 256) { hhi[i] = 0; hlo[i] = 0; }
  f32x4 bzv, brv, bhv, hv;
#pragma unroll
  for (int r = 0; r < 4; ++r) {
    bzv[r] = bz[cb + r]; brv[r] = br[cb + r]; bhv[r] = bh[cb + r]; hv[r] = 0.f;
  }
  __syncthreads();

  const u16* Mrow = M + (size_t)(nb0 + lm) * 3072;
  s16x8 Mn[2];
  Mn[0] = *(const s16x8*)&Mrow[q * 8];
  Mn[1] = *(const s16x8*)&Mrow[32 + q * 8];

  for (int t = 0; t < 48; ++t) {
    s16x8 Mc[2] = {Mn[0], Mn[1]};
    if (t < 47) {
      Mn[0] = *(const s16x8*)&Mrow[(t + 1) * 64 + q * 8];
      Mn[1] = *(const s16x8*)&Mrow[(t + 1) * 64 + 32 + q * 8];
    }
    f32x4 uzw, uzh, urw, urh;
#pragma unroll
    for (int r = 0; r < 4; ++r) { uzw[r] = 0.f; uzh[r] = 0.f; urw[r] = 0.f; urh[r] = 0.f; }
#pragma unroll
    for (int s = 0; s < 2; ++s) {
      s16x8 hh = *(const s16x8*)&hhi[lm * 72 + 32 * s + q * 8];
      s16x8 hl = *(const s16x8*)&hlo[lm * 72 + 32 * s + q * 8];
      uzw = __builtin_amdgcn_mfma_f32_16x16x32_bf16(afw[0][s], Mc[s], uzw, 0, 0, 0);
      uzh = __builtin_amdgcn_mfma_f32_16x16x32_bf16(afl[0][s], hh, uzh, 0, 0, 0);
      uzh = __builtin_amdgcn_mfma_f32_16x16x32_bf16(afl[0][s], hl, uzh, 0, 0, 0);
      urw = __builtin_amdgcn_mfma_f32_16x16x32_bf16(afw[1][s], Mc[s], urw, 0, 0, 0);
      urh = __builtin_amdgcn_mfma_f32_16x16x32_bf16(afl[1][s], hh, urh, 0, 0, 0);
      urh = __builtin_amdgcn_mfma_f32_16x16x32_bf16(afl[1][s], hl, urh, 0, 0, 0);
    }
    f32x4 zv, rv;
#pragma unroll
    for (int r = 0; r < 4; ++r) {
      zv[r] = sigm(uzw[r] + uzh[r] + bzv[r]);
      rv[r] = sigm(urw[r] + urh[r] + brv[r]);
    }
    {
      u16x4 phi, plo;
#pragma unroll
      for (int r = 0; r < 4; ++r) {
        float p = hv[r] * rv[r];
        u16 hi = f2b(p); phi[r] = hi; plo[r] = f2b(p - b2f(hi));
      }
      *(u16x4*)&rhi[lm * 72 + cb] = phi;
      *(u16x4*)&rlo[lm * 72 + cb] = plo;
    }
    __syncthreads();                   // h*r visible; all reads of h done
    f32x4 uhw, uhh;
#pragma unroll
    for (int r = 0; r < 4; ++r) { uhw[r] = 0.f; uhh[r] = 0.f; }
#pragma unroll
    for (int s = 0; s < 2; ++s) {
      s16x8 rh = *(const s16x8*)&rhi[lm * 72 + 32 * s + q * 8];
      s16x8 rl = *(const s16x8*)&rlo[lm * 72 + 32 * s + q * 8];
      uhw = __builtin_amdgcn_mfma_f32_16x16x32_bf16(afw[2][s], Mc[s], uhw, 0, 0, 0);
      uhh = __builtin_amdgcn_mfma_f32_16x16x32_bf16(afl[2][s], rh, uhh, 0, 0, 0);
      uhh = __builtin_amdgcn_mfma_f32_16x16x32_bf16(afl[2][s], rl, uhh, 0, 0, 0);
    }
    {
      u16x4 phi, plo;
#pragma unroll
      for (int r = 0; r < 4; ++r) {
        float th = tanh_f(uhw[r] + uhh[r] + bhv[r]);
        float hn = zv[r] * hv[r] + (1.f - zv[r]) * th;
        hv[r] = hn;
        u16 hi = f2b(hn); phi[r] = hi; plo[r] = f2b(hn - b2f(hi));
      }
      *(u16x4*)&hhi[lm * 72 + cb] = phi;
      *(u16x4*)&hlo[lm * 72 + cb] = plo;
    }
    __syncthreads();                   // h_{t+1} visible; r-buffer reads done
  }
#pragma unroll
  for (int r = 0; r < 4; ++r)
    out[(size_t)(nb0 + lm) * 64 + cb + r] = hv[r];
}

extern "C" void kernel_launch(void* const* d_in, const int* in_sizes, int n_in,
                              void* d_out, int out_size, void* d_ws, size_t ws_size,
                              hipStream_t stream) {
  const float* x   = (const float*)d_in[0];
  const float* adj = (const float*)d_in[1];
  const float* fcw = (const float*)d_in[2];
  const float* fcb = (const float*)d_in[3];
  const float* Wz  = (const float*)d_in[4];
  const float* Wr  = (const float*)d_in[5];
  const float* Wh  = (const float*)d_in[6];
  const float* Lz  = (const float*)d_in[7];
  const float* Lr  = (const float*)d_in[8];
  const float* Lh  = (const float*)d_in[9];
  const float* bz  = (const float*)d_in[10];
  const float* br  = (const float*)d_in[11];
  const float* bh  = (const float*)d_in[12];
  char* ws = (char*)d_ws;
  // ws layout (bytes):
  u8*  xht  = (u8*)(ws);                           // [3072][4096] fp8: 12,582,912
  u8*  adj8 = (u8*)(ws + (size_t)12582912);        // [4096][4096] fp8: 16,777,216
  u16* Mm   = (u16*)(ws + (size_t)29360128);       // [4096][3072] bf16: 25,165,824
  u16* wct  = (u16*)(ws + (size_t)54525952);       // 24 KB
  u16* lbt  = (u16*)(ws + (size_t)54550528);       // 24 KB
  float* outp = (float*)d_out;

  hipLaunchKernelGGL(kpre, dim3(5683), dim3(256), 0, stream,
                     adj, adj8, fcw, fcb, x, xht, Wz, Wr, Wh, Lz, Lr, Lh, wct, lbt);
  hipLaunchKernelGGL(k2, dim3(16, 16), dim3(512), 0, stream, adj8, xht, Mm);
  hipLaunchKernelGGL(k3, dim3(256), dim3(256), 0, stream, Mm, wct, lbt, bz, br, bh, outp);
}

// Round 2
// 285.949 us; speedup vs baseline: 1.0595x; 1.0595x over previous
//
#include <hip/hip_runtime.h>

typedef unsigned short u16;
typedef unsigned char u8;
typedef short s16x8 __attribute__((ext_vector_type(8)));
typedef unsigned short u16x4 __attribute__((ext_vector_type(4)));
typedef float f32x4 __attribute__((ext_vector_type(4)));
typedef int i32x4 __attribute__((ext_vector_type(4)));
typedef int i32x8 __attribute__((ext_vector_type(8)));

#define AS1 __attribute__((address_space(1)))
#define AS3 __attribute__((address_space(3)))

// async global->LDS, 16B per lane; LDS dest = wave-uniform base + lane*16
__device__ __forceinline__ void g2l16(const void* g, void* l) {
  __builtin_amdgcn_global_load_lds((const AS1 void*)g, (AS3 void*)l, 16, 0, 0);
}

__device__ __forceinline__ float b2f(u16 u) {
  union { unsigned int i; float f; } x; x.i = ((unsigned int)u) << 16; return x.f;
}
__device__ __forceinline__ u16 f2b(float f) {  // round-to-nearest-even
  unsigned int u = __builtin_bit_cast(unsigned int, f);
  return (u16)((u + 0x7fffu + ((u >> 16) & 1u)) >> 16);
}
__device__ __forceinline__ u8 f2e4m3(float v) {
  int p = __builtin_amdgcn_cvt_pk_fp8_f32(v, 0.f, 0, false);
  return (u8)(p & 0xff);
}
__device__ __forceinline__ float sigm(float x) { return 1.f / (1.f + __expf(-x)); }
__device__ __forceinline__ float tanh_f(float x) { return 2.f / (1.f + __expf(-2.f * x)) - 1.f; }

// dims: T=48 N=4096 F_IN=H1=F_OUT=64; TH = 3072

// ---------------- kpre: adj->fp8 + weight prep + k1 (XHT), one launch ----------------
// blocks [0,4096): adj fp32->fp8 e4m3 scaled x4096 (coalesced)
// blocks [4096,4144): wct;  [4144,4147): lbt;  [4147,5683): XHT tiles
__global__ __launch_bounds__(256) void kpre(
    const float* __restrict__ a, u8* __restrict__ ab,
    const float* __restrict__ fcw, const float* __restrict__ fcb,
    const float* __restrict__ x, u8* __restrict__ xht,
    const float* __restrict__ Wz, const float* __restrict__ Wr, const float* __restrict__ Wh,
    const float* __restrict__ Lz, const float* __restrict__ Lr, const float* __restrict__ Lh,
    u16* __restrict__ wct, u16* __restrict__ lbt) {
  int b = blockIdx.x, tid = threadIdx.x;
  if (b < 4096) {
    size_t idx = (size_t)b * 256 + tid;   // lane-contiguous float4 index
    const float4* src = (const float4*)a;
    unsigned int* dst = (unsigned int*)ab;
#pragma unroll
    for (int k = 0; k < 4; ++k) {
      float4 v = src[idx + (size_t)k * 1048576];
      unsigned int p = __builtin_amdgcn_cvt_pk_fp8_f32(v.x * 4096.f, v.y * 4096.f, 0, false);
      p = __builtin_amdgcn_cvt_pk_fp8_f32(v.z * 4096.f, v.w * 4096.f, p, true);
      dst[idx + (size_t)k * 1048576] = p;
    }
    return;
  }
  if (b < 4144) {
    int idx = (b - 4096) * 256 + tid;  // 0..12287
    int c_cat = idx >> 6, hh = idx & 63;
    int g = c_cat >> 6, c = c_cat & 63;
    const float* W = (g == 0) ? Wz : (g == 1) ? Wr : Wh;
    const float* L = (g == 0) ? Lz : (g == 1) ? Lr : Lh;
    float acc = 0.f;
    for (int m = 0; m < 64; ++m) acc += W[hh * 64 + m] * L[m * 64 + c];
    wct[c_cat * 64 + hh] = f2b(acc);
    return;
  }
  if (b < 4147) {
    int g = b - 4144;
    const float* L = (g == 0) ? Lz : (g == 1) ? Lr : Lh;
    for (int i = 0; i < 16; ++i) {
      int idx = tid * 16 + i; int c = idx >> 6, hh = idx & 63;
      lbt[g * 4096 + c * 64 + hh] = f2b(L[(64 + hh) * 64 + c]);
    }
    return;
  }
  // ---- XHT part: kb in [0,1536): t = kb>>5, n0 = (kb&31)*128 ----
  int kb = b - 4147;
  int t = kb >> 5, n0 = (kb & 31) * 128;
  __shared__ __align__(16) u16 xs[128 * 72];   // padded: 2-way banks
  __shared__ __align__(16) u16 fw[64 * 72];
  __shared__ __align__(16) u8 xh8[64 * 128];   // [h][node]
  __shared__ float fb[64];
  int w = tid >> 6, l = tid & 63;
#pragma unroll
  for (int i = 0; i < 16; ++i) {       // fw[h][f] = fc_w[f][h], coalesced fp32 reads
    int idx = tid + i * 256;
    int h = idx & 63, f = idx >> 6;
    fw[h * 72 + f] = f2b(fcw[f * 64 + h]);
  }
  const float4* xg = (const float4*)(x + ((size_t)t * 4096 + n0) * 64);
#pragma unroll
  for (int i = 0; i < 8; ++i) {
    int f = tid + i * 256;             // lane-contiguous float4 index
    float4 v = xg[f];
    u16x4 p; p[0] = f2b(v.x); p[1] = f2b(v.y); p[2] = f2b(v.z); p[3] = f2b(v.w);
    *(u16x4*)&xs[(f >> 4) * 72 + (f & 15) * 4] = p;
  }
  if (tid < 64) fb[tid] = fcb[tid];
  __syncthreads();

  int lm = l & 15, q = l >> 4;
  f32x4 acc[4][2];
#pragma unroll
  for (int i = 0; i < 4; ++i)
#pragma unroll
    for (int j = 0; j < 2; ++j)
#pragma unroll
      for (int r = 0; r < 4; ++r) acc[i][j][r] = 0.f;
#pragma unroll
  for (int s = 0; s < 2; ++s) {
    s16x8 af[4], bf[2];
#pragma unroll
    for (int i = 0; i < 4; ++i) af[i] = *(const s16x8*)&fw[(16 * i + lm) * 72 + 32 * s + q * 8];
#pragma unroll
    for (int j = 0; j < 2; ++j) bf[j] = *(const s16x8*)&xs[(32 * w + 16 * j + lm) * 72 + 32 * s + q * 8];
#pragma unroll
    for (int i = 0; i < 4; ++i)
#pragma unroll
      for (int j = 0; j < 2; ++j)
        acc[i][j] = __builtin_amdgcn_mfma_f32_16x16x32_bf16(af[i], bf[j], acc[i][j], 0, 0, 0);
  }
#pragma unroll
  for (int i = 0; i < 4; ++i)
#pragma unroll
    for (int j = 0; j < 2; ++j) {
      int node = 32 * w + 16 * j + lm;
      int h0 = 16 * i + q * 4;
#pragma unroll
      for (int r = 0; r < 4; ++r) {
        float v = acc[i][j][r] + fb[h0 + r];
        xh8[(h0 + r) * 128 + node] = f2e4m3(v > 0.f ? v : 0.f);
      }
    }
  __syncthreads();
  {
    int h = tid >> 2, seg = tid & 3;   // 32 bytes per thread
    u8* dst = xht + (size_t)(t * 64 + h) * 4096 + n0 + seg * 32;
    const u8* src = &xh8[h * 128 + seg * 32];
    *(i32x4*)dst = *(const i32x4*)src;
    *(i32x4*)(dst + 16) = *(const i32x4*)(src + 16);
  }
}

// ---------------- k2: M = adj8 @ XH8, MX fp8 K=128 ----------------
// 128x192 tile, 256 threads (4 waves as 2x2, wave tile 64x96), grid (16,32)
// = 512 blocks = 2 blocks/CU -- cross-block overlap hides the pre-barrier
// vmcnt drain (round-1 lesson: 1 block/CU serializes the stage latency).
// A operand: direct global->VGPR (wave-exclusive rows, no reuse -> no LDS).
// B operand: LDS double-buffered (2 x 24KB), rotation swizzle, ONE barrier
// per K-step. A-loads issued before the B-stage so waiting on a8 leaves the
// 24 staging loads in flight (in-order vmcnt retire).
__global__ __launch_bounds__(256, 2) void k2(
    const u8* __restrict__ A, const u8* __restrict__ B, u16* __restrict__ M) {
  __shared__ __align__(16) u8 sh[49152];        // 2 x (192 rows x 128B)
  int tid = threadIdx.x, w = tid >> 6, l = tid & 63;
  int nt = blockIdx.x, mt = blockIdx.y;
  const u8* Ab = A + (size_t)mt * 128 * 4096;
  const u8* Bb = B + (size_t)nt * 192 * 4096;
  int lm = l & 15, q = l >> 4;
  int wm = w >> 1, wn = w & 1;                  // wave tile: rows 64*wm, cols 96*wn
  int srow = l >> 3, scol = l & 7;
  f32x4 acc[4][6];
#pragma unroll
  for (int i = 0; i < 4; ++i)
#pragma unroll
    for (int j = 0; j < 6; ++j)
#pragma unroll
      for (int r = 0; r < 4; ++r) acc[i][j][r] = 0.f;

#define STAGE_B(bsel, kk)                                                     \
  do {                                                                        \
    _Pragma("unroll") for (int j = 0; j < 6; ++j) {                           \
      int r0 = 48 * w + 8 * j;                                                \
      int row = r0 + srow;                                                    \
      int c = (scol - row) & 7;                                               \
      g2l16(Bb + (size_t)row * 4096 + (kk) + c * 16,                          \
            sh + (bsel) * 24576 + r0 * 128);                                  \
    }                                                                         \
  } while (0)

  STAGE_B(0, 0);
  __syncthreads();                     // buf0 ready

  for (int it = 0; it < 32; ++it) {
    int k0b = it * 128;
    int cur = it & 1;
    // A fragments first (vmcnt retires in issue order: waiting for a8 leaves
    // the younger staging g2l16s outstanding).
    i32x8 a8[4];
#pragma unroll
    for (int i = 0; i < 4; ++i) {
      int ra = 64 * wm + 16 * i + lm;
      a8[i] = *(const i32x8*)(Ab + (size_t)ra * 4096 + k0b + q * 32);
    }
    if (it < 31) STAGE_B(cur ^ 1, k0b + 128);   // prefetch next K-tile of B
    const u8* Bs = sh + cur * 24576;
#pragma unroll
    for (int j = 0; j < 6; ++j) {
      int rb = 96 * wn + 16 * j + lm;
      int q0 = (2 * q + rb) & 7, q1 = (2 * q + 1 + rb) & 7;
      i32x4 lo = *(const i32x4*)&Bs[rb * 128 + q0 * 16];
      i32x4 hi = *(const i32x4*)&Bs[rb * 128 + q1 * 16];
      i32x8 b8 = __builtin_shufflevector(lo, hi, 0, 1, 2, 3, 4, 5, 6, 7);
#pragma unroll
      for (int i = 0; i < 4; ++i)
        acc[i][j] = __builtin_amdgcn_mfma_scale_f32_16x16x128_f8f6f4(
            a8[i], b8, acc[i][j], 0, 0, 0, 127, 0, 127);  // fmt=fp8, scale=2^0
    }
    __syncthreads();                   // next buffer staged; this buffer free
  }
#undef STAGE_B

  // epilogue: 2-pass transpose through LDS. tb = [64][200] u16 (25.6KB)
  u16* tb = (u16*)sh;
  const float sc = 1.f / 4096.f;
#pragma unroll
  for (int p = 0; p < 2; ++p) {
    if (p) __syncthreads();            // pass-0 LDS reads done before overwrite
    if (wm == p) {
#pragma unroll
      for (int i = 0; i < 4; ++i)
#pragma unroll
        for (int j = 0; j < 6; ++j)
#pragma unroll
          for (int r = 0; r < 4; ++r)
            tb[(16 * i + 4 * q + r) * 200 + 96 * wn + 16 * j + lm] = f2b(acc[i][j][r] * sc);
    }
    __syncthreads();
    int row = tid >> 2, seg = tid & 3;   // 64 rows x 384B; 96B (48 u16) per thread
    u16* dst = M + (size_t)(mt * 128 + p * 64 + row) * 3072 + nt * 192 + seg * 48;
    const u16* src = &tb[row * 200 + seg * 48];
#pragma unroll
    for (int v = 0; v < 6; ++v)
      *(i32x4*)(dst + 8 * v) = *(const i32x4*)(src + 8 * v);
  }
}

// ---------------- k3: GRU scan; weights in regs, 2 barriers/step, split acc chains ----------------
__global__ __launch_bounds__(256) void k3(
    const u16* __restrict__ M, const u16* __restrict__ wct, const u16* __restrict__ lbt,
    const float* __restrict__ bz, const float* __restrict__ br, const float* __restrict__ bh,
    float* __restrict__ out) {
  __shared__ __align__(16) u16 hhi[16 * 72], hlo[16 * 72];
  __shared__ __align__(16) u16 rhi[16 * 72], rlo[16 * 72];
  int tid = threadIdx.x, w = tid >> 6, l = tid & 63;
  int nb0 = blockIdx.x * 16;
  int lm = l & 15, q = l >> 4;
  int cb = 16 * w + q * 4;
  s16x8 afw[3][2], afl[3][2];
#pragma unroll
  for (int g = 0; g < 3; ++g)
#pragma unroll
    for (int s = 0; s < 2; ++s) {
      afw[g][s] = *(const s16x8*)&wct[(size_t)(g * 64 + 16 * w + lm) * 64 + 32 * s + q * 8];
      afl[g][s] = *(const s16x8*)&lbt[(size_t)(g * 64 + 16 * w + lm) * 64 + 32 * s + q * 8];
    }
  for (int i = tid; i < 16 * 72; i += 256) { hhi[i] = 0; hlo[i] = 0; }
  f32x4 bzv, brv, bhv, hv;
#pragma unroll
  for (int r = 0; r < 4; ++r) {
    bzv[r] = bz[cb + r]; brv[r] = br[cb + r]; bhv[r] = bh[cb + r]; hv[r] = 0.f;
  }
  __syncthreads();

  const u16* Mrow = M + (size_t)(nb0 + lm) * 3072;
  s16x8 Mn[2];
  Mn[0] = *(const s16x8*)&Mrow[q * 8];
  Mn[1] = *(const s16x8*)&Mrow[32 + q * 8];

  for (int t = 0; t < 48; ++t) {
    s16x8 Mc[2] = {Mn[0], Mn[1]};
    if (t < 47) {
      Mn[0] = *(const s16x8*)&Mrow[(t + 1) * 64 + q * 8];
      Mn[1] = *(const s16x8*)&Mrow[(t + 1) * 64 + 32 + q * 8];
    }
    f32x4 uzw, uzh, urw, urh;
#pragma unroll
    for (int r = 0; r < 4; ++r) { uzw[r] = 0.f; uzh[r] = 0.f; urw[r] = 0.f; urh[r] = 0.f; }
#pragma unroll
    for (int s = 0; s < 2; ++s) {
      s16x8 hh = *(const s16x8*)&hhi[lm * 72 + 32 * s + q * 8];
      s16x8 hl = *(const s16x8*)&hlo[lm * 72 + 32 * s + q * 8];
      uzw = __builtin_amdgcn_mfma_f32_16x16x32_bf16(afw[0][s], Mc[s], uzw, 0, 0, 0);
      uzh = __builtin_amdgcn_mfma_f32_16x16x32_bf16(afl[0][s], hh, uzh, 0, 0, 0);
      uzh = __builtin_amdgcn_mfma_f32_16x16x32_bf16(afl[0][s], hl, uzh, 0, 0, 0);
      urw = __builtin_amdgcn_mfma_f32_16x16x32_bf16(afw[1][s], Mc[s], urw, 0, 0, 0);
      urh = __builtin_amdgcn_mfma_f32_16x16x32_bf16(afl[1][s], hh, urh, 0, 0, 0);
      urh = __builtin_amdgcn_mfma_f32_16x16x32_bf16(afl[1][s], hl, urh, 0, 0, 0);
    }
    f32x4 zv, rv;
#pragma unroll
    for (int r = 0; r < 4; ++r) {
      zv[r] = sigm(uzw[r] + uzh[r] + bzv[r]);
      rv[r] = sigm(urw[r] + urh[r] + brv[r]);
    }
    {
      u16x4 phi, plo;
#pragma unroll
      for (int r = 0; r < 4; ++r) {
        float p = hv[r] * rv[r];
        u16 hi = f2b(p); phi[r] = hi; plo[r] = f2b(p - b2f(hi));
      }
      *(u16x4*)&rhi[lm * 72 + cb] = phi;
      *(u16x4*)&rlo[lm * 72 + cb] = plo;
    }
    __syncthreads();                   // h*r visible; all reads of h done
    f32x4 uhw, uhh;
#pragma unroll
    for (int r = 0; r < 4; ++r) { uhw[r] = 0.f; uhh[r] = 0.f; }
#pragma unroll
    for (int s = 0; s < 2; ++s) {
      s16x8 rh = *(const s16x8*)&rhi[lm * 72 + 32 * s + q * 8];
      s16x8 rl = *(const s16x8*)&rlo[lm * 72 + 32 * s + q * 8];
      uhw = __builtin_amdgcn_mfma_f32_16x16x32_bf16(afw[2][s], Mc[s], uhw, 0, 0, 0);
      uhh = __builtin_amdgcn_mfma_f32_16x16x32_bf16(afl[2][s], rh, uhh, 0, 0, 0);
      uhh = __builtin_amdgcn_mfma_f32_16x16x32_bf16(afl[2][s], rl, uhh, 0, 0, 0);
    }
    {
      u16x4 phi, plo;
#pragma unroll
      for (int r = 0; r < 4; ++r) {
        float th = tanh_f(uhw[r] + uhh[r] + bhv[r]);
        float hn = zv[r] * hv[r] + (1.f - zv[r]) * th;
        hv[r] = hn;
        u16 hi = f2b(hn); phi[r] = hi; plo[r] = f2b(hn - b2f(hi));
      }
      *(u16x4*)&hhi[lm * 72 + cb] = phi;
      *(u16x4*)&hlo[lm * 72 + cb] = plo;
    }
    __syncthreads();                   // h_{t+1} visible; r-buffer reads done
  }
#pragma unroll
  for (int r = 0; r < 4; ++r)
    out[(size_t)(nb0 + lm) * 64 + cb + r] = hv[r];
}

extern "C" void kernel_launch(void* const* d_in, const int* in_sizes, int n_in,
                              void* d_out, int out_size, void* d_ws, size_t ws_size,
                              hipStream_t stream) {
  const float* x   = (const float*)d_in[0];
  const float* adj = (const float*)d_in[1];
  const float* fcw = (const float*)d_in[2];
  const float* fcb = (const float*)d_in[3];
  const float* Wz  = (const float*)d_in[4];
  const float* Wr  = (const float*)d_in[5];
  const float* Wh  = (const float*)d_in[6];
  const float* Lz  = (const float*)d_in[7];
  const float* Lr  = (const float*)d_in[8];
  const float* Lh  = (const float*)d_in[9];
  const float* bz  = (const float*)d_in[10];
  const float* br  = (const float*)d_in[11];
  const float* bh  = (const float*)d_in[12];
  char* ws = (char*)d_ws;
  // ws layout (bytes):
  u8*  xht  = (u8*)(ws);                           // [3072][4096] fp8: 12,582,912
  u8*  adj8 = (u8*)(ws + (size_t)12582912);        // [4096][4096] fp8: 16,777,216
  u16* Mm   = (u16*)(ws + (size_t)29360128);       // [4096][3072] bf16: 25,165,824
  u16* wct  = (u16*)(ws + (size_t)54525952);       // 24 KB
  u16* lbt  = (u16*)(ws + (size_t)54550528);       // 24 KB
  float* outp = (float*)d_out;

  hipLaunchKernelGGL(kpre, dim3(5683), dim3(256), 0, stream,
                     adj, adj8, fcw, fcb, x, xht, Wz, Wr, Wh, Lz, Lr, Lh, wct, lbt);
  hipLaunchKernelGGL(k2, dim3(16, 32), dim3(256), 0, stream, adj8, xht, Mm);
  hipLaunchKernelGGL(k3, dim3(256), dim3(256), 0, stream, Mm, wct, lbt, bz, br, bh, outp);
}

// Round 3
// 263.319 us; speedup vs baseline: 1.1506x; 1.0859x over previous
//
#include <hip/hip_runtime.h>

typedef unsigned short u16;
typedef unsigned char u8;
typedef short s16x8 __attribute__((ext_vector_type(8)));
typedef unsigned short u16x4 __attribute__((ext_vector_type(4)));
typedef float f32x4 __attribute__((ext_vector_type(4)));
typedef int i32x4 __attribute__((ext_vector_type(4)));
typedef int i32x8 __attribute__((ext_vector_type(8)));

#define AS1 __attribute__((address_space(1)))
#define AS3 __attribute__((address_space(3)))

// async global->LDS, 16B per lane; LDS dest = wave-uniform base + lane*16
__device__ __forceinline__ void g2l16(const void* g, void* l) {
  __builtin_amdgcn_global_load_lds((const AS1 void*)g, (AS3 void*)l, 16, 0, 0);
}

__device__ __forceinline__ float b2f(u16 u) {
  union { unsigned int i; float f; } x; x.i = ((unsigned int)u) << 16; return x.f;
}
__device__ __forceinline__ u16 f2b(float f) {  // round-to-nearest-even
  unsigned int u = __builtin_bit_cast(unsigned int, f);
  return (u16)((u + 0x7fffu + ((u >> 16) & 1u)) >> 16);
}
__device__ __forceinline__ u8 f2e4m3(float v) {
  int p = __builtin_amdgcn_cvt_pk_fp8_f32(v, 0.f, 0, false);
  return (u8)(p & 0xff);
}
__device__ __forceinline__ float sigm(float x) { return 1.f / (1.f + __expf(-x)); }
__device__ __forceinline__ float tanh_f(float x) { return 2.f / (1.f + __expf(-2.f * x)) - 1.f; }

// LDS-only barrier: waits for this wave's LDS ops, then syncs. Deliberately
// does NOT drain vmcnt -- the only cross-wave shared state is in LDS; global
// loads in flight (M prefetch in k3) are lane-private and their use is
// dependency-tracked by the compiler's own waitcnt insertion.
__device__ __forceinline__ void lds_barrier() {
  asm volatile("s_waitcnt lgkmcnt(0)\n\ts_barrier" ::: "memory");
}

// dims: T=48 N=4096 F_IN=H1=F_OUT=64; TH = 3072

// ---------------- kpre: adj->fp8 + weight prep + k1 (XHT), one launch ----------------
// blocks [0,4096): adj fp32->fp8 e4m3 scaled x4096 (coalesced)
// blocks [4096,4144): wct;  [4144,4147): lbt;  [4147,5683): XHT tiles
__global__ __launch_bounds__(256) void kpre(
    const float* __restrict__ a, u8* __restrict__ ab,
    const float* __restrict__ fcw, const float* __restrict__ fcb,
    const float* __restrict__ x, u8* __restrict__ xht,
    const float* __restrict__ Wz, const float* __restrict__ Wr, const float* __restrict__ Wh,
    const float* __restrict__ Lz, const float* __restrict__ Lr, const float* __restrict__ Lh,
    u16* __restrict__ wct, u16* __restrict__ lbt) {
  int b = blockIdx.x, tid = threadIdx.x;
  if (b < 4096) {
    size_t idx = (size_t)b * 256 + tid;   // lane-contiguous float4 index
    const float4* src = (const float4*)a;
    unsigned int* dst = (unsigned int*)ab;
#pragma unroll
    for (int k = 0; k < 4; ++k) {
      float4 v = src[idx + (size_t)k * 1048576];
      unsigned int p = __builtin_amdgcn_cvt_pk_fp8_f32(v.x * 4096.f, v.y * 4096.f, 0, false);
      p = __builtin_amdgcn_cvt_pk_fp8_f32(v.z * 4096.f, v.w * 4096.f, p, true);
      dst[idx + (size_t)k * 1048576] = p;
    }
    return;
  }
  if (b < 4144) {
    int idx = (b - 4096) * 256 + tid;  // 0..12287
    int c_cat = idx >> 6, hh = idx & 63;
    int g = c_cat >> 6, c = c_cat & 63;
    const float* W = (g == 0) ? Wz : (g == 1) ? Wr : Wh;
    const float* L = (g == 0) ? Lz : (g == 1) ? Lr : Lh;
    float acc = 0.f;
    for (int m = 0; m < 64; ++m) acc += W[hh * 64 + m] * L[m * 64 + c];
    wct[c_cat * 64 + hh] = f2b(acc);
    return;
  }
  if (b < 4147) {
    int g = b - 4144;
    const float* L = (g == 0) ? Lz : (g == 1) ? Lr : Lh;
    for (int i = 0; i < 16; ++i) {
      int idx = tid * 16 + i; int c = idx >> 6, hh = idx & 63;
      lbt[g * 4096 + c * 64 + hh] = f2b(L[(64 + hh) * 64 + c]);
    }
    return;
  }
  // ---- XHT part: kb in [0,1536): t = kb>>5, n0 = (kb&31)*128 ----
  int kb = b - 4147;
  int t = kb >> 5, n0 = (kb & 31) * 128;
  __shared__ __align__(16) u16 xs[128 * 72];   // padded: 2-way banks
  __shared__ __align__(16) u16 fw[64 * 72];
  __shared__ __align__(16) u8 xh8[64 * 128];   // [h][node]
  __shared__ float fb[64];
  int w = tid >> 6, l = tid & 63;
#pragma unroll
  for (int i = 0; i < 16; ++i) {       // fw[h][f] = fc_w[f][h], coalesced fp32 reads
    int idx = tid + i * 256;
    int h = idx & 63, f = idx >> 6;
    fw[h * 72 + f] = f2b(fcw[f * 64 + h]);
  }
  const float4* xg = (const float4*)(x + ((size_t)t * 4096 + n0) * 64);
#pragma unroll
  for (int i = 0; i < 8; ++i) {
    int f = tid + i * 256;             // lane-contiguous float4 index
    float4 v = xg[f];
    u16x4 p; p[0] = f2b(v.x); p[1] = f2b(v.y); p[2] = f2b(v.z); p[3] = f2b(v.w);
    *(u16x4*)&xs[(f >> 4) * 72 + (f & 15) * 4] = p;
  }
  if (tid < 64) fb[tid] = fcb[tid];
  __syncthreads();

  int lm = l & 15, q = l >> 4;
  f32x4 acc[4][2];
#pragma unroll
  for (int i = 0; i < 4; ++i)
#pragma unroll
    for (int j = 0; j < 2; ++j)
#pragma unroll
      for (int r = 0; r < 4; ++r) acc[i][j][r] = 0.f;
#pragma unroll
  for (int s = 0; s < 2; ++s) {
    s16x8 af[4], bf[2];
#pragma unroll
    for (int i = 0; i < 4; ++i) af[i] = *(const s16x8*)&fw[(16 * i + lm) * 72 + 32 * s + q * 8];
#pragma unroll
    for (int j = 0; j < 2; ++j) bf[j] = *(const s16x8*)&xs[(32 * w + 16 * j + lm) * 72 + 32 * s + q * 8];
#pragma unroll
    for (int i = 0; i < 4; ++i)
#pragma unroll
      for (int j = 0; j < 2; ++j)
        acc[i][j] = __builtin_amdgcn_mfma_f32_16x16x32_bf16(af[i], bf[j], acc[i][j], 0, 0, 0);
  }
#pragma unroll
  for (int i = 0; i < 4; ++i)
#pragma unroll
    for (int j = 0; j < 2; ++j) {
      int node = 32 * w + 16 * j + lm;
      int h0 = 16 * i + q * 4;
#pragma unroll
      for (int r = 0; r < 4; ++r) {
        float v = acc[i][j][r] + fb[h0 + r];
        xh8[(h0 + r) * 128 + node] = f2e4m3(v > 0.f ? v : 0.f);
      }
    }
  __syncthreads();
  {
    int h = tid >> 2, seg = tid & 3;   // 32 bytes per thread
    u8* dst = xht + (size_t)(t * 64 + h) * 4096 + n0 + seg * 32;
    const u8* src = &xh8[h * 128 + seg * 32];
    *(i32x4*)dst = *(const i32x4*)src;
    *(i32x4*)(dst + 16) = *(const i32x4*)(src + 16);
  }
}

// ---------------- k2: M = adj8 @ XH8, MX fp8 K=128, 128x192 tile, rotation swizzle ----------------
// (round-0 structure: both operands staged via g2l16, 2 barriers/K-step,
// grid (16,32) = 2 blocks/CU so cross-block overlap hides the barrier drain.
// Round-1/2 lesson: A-direct-global (lane-stride 4096B, uncoalesced) and
// 1-block/CU variants both regress.)
__global__ __launch_bounds__(256) void k2(
    const u8* __restrict__ A, const u8* __restrict__ B, u16* __restrict__ M) {
  __shared__ __align__(16) u8 sh[40960];
  u8* As = sh;                    // 128 x 128B = 16KB
  u8* Bs = sh + 16384;            // 192 x 128B = 24KB
  int tid = threadIdx.x, w = tid >> 6, l = tid & 63;
  int nt = blockIdx.x, mt = blockIdx.y;
  const u8* Ab = A + (size_t)mt * 128 * 4096;
  const u8* Bb = B + (size_t)nt * 192 * 4096;
  int lm = l & 15, q = l >> 4;
  int wm = w >> 1, wn = w & 1;
  f32x4 acc[4][6];
#pragma unroll
  for (int i = 0; i < 4; ++i)
#pragma unroll
    for (int j = 0; j < 6; ++j)
#pragma unroll
      for (int r = 0; r < 4; ++r) acc[i][j][r] = 0.f;
  int srow = l >> 3;
  for (int k0b = 0; k0b < 4096; k0b += 128) {
#pragma unroll
    for (int j = 0; j < 4; ++j) {      // A: 32 rows/wave
      int r0 = 32 * w + 8 * j;
      int row = r0 + srow;
      int c = ((l & 7) - row) & 7;
      g2l16(Ab + (size_t)row * 4096 + k0b + c * 16, (char*)As + r0 * 128);
    }
#pragma unroll
    for (int j = 0; j < 6; ++j) {      // B: 48 rows/wave
      int r0 = 48 * w + 8 * j;
      int row = r0 + srow;
      int c = ((l & 7) - row) & 7;
      g2l16(Bb + (size_t)row * 4096 + k0b + c * 16, (char*)Bs + r0 * 128);
    }
    __syncthreads();
    i32x8 a8[4];
#pragma unroll
    for (int i = 0; i < 4; ++i) {
      int ra = 64 * wm + 16 * i + lm;
      int p0 = (2 * q + ra) & 7, p1 = (2 * q + 1 + ra) & 7;
      i32x4 lo = *(const i32x4*)&As[ra * 128 + p0 * 16];
      i32x4 hi = *(const i32x4*)&As[ra * 128 + p1 * 16];
      a8[i] = __builtin_shufflevector(lo, hi, 0, 1, 2, 3, 4, 5, 6, 7);
    }
#pragma unroll
    for (int j = 0; j < 6; ++j) {
      int rb = 96 * wn + 16 * j + lm;
      int q0 = (2 * q + rb) & 7, q1 = (2 * q + 1 + rb) & 7;
      i32x4 lo2 = *(const i32x4*)&Bs[rb * 128 + q0 * 16];
      i32x4 hi2 = *(const i32x4*)&Bs[rb * 128 + q1 * 16];
      i32x8 b8 = __builtin_shufflevector(lo2, hi2, 0, 1, 2, 3, 4, 5, 6, 7);
#pragma unroll
      for (int i = 0; i < 4; ++i)
        acc[i][j] = __builtin_amdgcn_mfma_scale_f32_16x16x128_f8f6f4(
            a8[i], b8, acc[i][j], 0, 0, 0, 127, 0, 127);  // fmt=fp8, scale=2^0
    }
    __syncthreads();
  }
  // epilogue: 2-pass transpose through LDS. tb = [64][200] u16 (25.6KB)
  u16* tb = (u16*)sh;
  const float sc = 1.f / 4096.f;
#pragma unroll
  for (int p = 0; p < 2; ++p) {
    if (p) __syncthreads();            // pass-0 LDS reads done before overwrite
    if (wm == p) {
#pragma unroll
      for (int i = 0; i < 4; ++i)
#pragma unroll
        for (int j = 0; j < 6; ++j)
#pragma unroll
          for (int r = 0; r < 4; ++r)
            tb[(16 * i + 4 * q + r) * 200 + 96 * wn + 16 * j + lm] = f2b(acc[i][j][r] * sc);
    }
    __syncthreads();
    int row = tid >> 2, seg = tid & 3;   // 64 rows x 384B; 96B (48 u16) per thread
    u16* dst = M + (size_t)(mt * 128 + p * 64 + row) * 3072 + nt * 192 + seg * 48;
    const u16* src = &tb[row * 200 + seg * 48];
#pragma unroll
    for (int v = 0; v < 6; ++v)
      *(i32x4*)(dst + 8 * v) = *(const i32x4*)(src + 8 * v);
  }
}

// ---------------- k3: GRU scan; weights in regs, 2 LDS-only barriers/step ----------------
__global__ __launch_bounds__(256) void k3(
    const u16* __restrict__ M, const u16* __restrict__ wct, const u16* __restrict__ lbt,
    const float* __restrict__ bz, const float* __restrict__ br, const float* __restrict__ bh,
    float* __restrict__ out) {
  __shared__ __align__(16) u16 hhi[16 * 72], hlo[16 * 72];
  __shared__ __align__(16) u16 rhi[16 * 72], rlo[16 * 72];
  int tid = threadIdx.x, w = tid >> 6, l = tid & 63;
  int nb0 = blockIdx.x * 16;
  int lm = l & 15, q = l >> 4;
  int cb = 16 * w + q * 4;
  s16x8 afw[3][2], afl[3][2];
#pragma unroll
  for (int g = 0; g < 3; ++g)
#pragma unroll
    for (int s = 0; s < 2; ++s) {
      afw[g][s] = *(const s16x8*)&wct[(size_t)(g * 64 + 16 * w + lm) * 64 + 32 * s + q * 8];
      afl[g][s] = *(const s16x8*)&lbt[(size_t)(g * 64 + 16 * w + lm) * 64 + 32 * s + q * 8];
    }
  for (int i = tid; i < 16 * 72; i += 256) { hhi[i] = 0; hlo[i] = 0; }
  f32x4 bzv, brv, bhv, hv;
#pragma unroll
  for (int r = 0; r < 4; ++r) {
    bzv[r] = bz[cb + r]; brv[r] = br[cb + r]; bhv[r] = bh[cb + r]; hv[r] = 0.f;
  }
  __syncthreads();

  const u16* Mrow = M + (size_t)(nb0 + lm) * 3072;
  s16x8 Mn[2];
  Mn[0] = *(const s16x8*)&Mrow[q * 8];
  Mn[1] = *(const s16x8*)&Mrow[32 + q * 8];

  for (int t = 0; t < 48; ++t) {
    s16x8 Mc[2] = {Mn[0], Mn[1]};
    if (t < 47) {
      Mn[0] = *(const s16x8*)&Mrow[(t + 1) * 64 + q * 8];
      Mn[1] = *(const s16x8*)&Mrow[(t + 1) * 64 + 32 + q * 8];
    }
    f32x4 uzw, uzh, urw, urh;
#pragma unroll
    for (int r = 0; r < 4; ++r) { uzw[r] = 0.f; uzh[r] = 0.f; urw[r] = 0.f; urh[r] = 0.f; }
#pragma unroll
    for (int s = 0; s < 2; ++s) {
      s16x8 hh = *(const s16x8*)&hhi[lm * 72 + 32 * s + q * 8];
      s16x8 hl = *(const s16x8*)&hlo[lm * 72 + 32 * s + q * 8];
      uzw = __builtin_amdgcn_mfma_f32_16x16x32_bf16(afw[0][s], Mc[s], uzw, 0, 0, 0);
      uzh = __builtin_amdgcn_mfma_f32_16x16x32_bf16(afl[0][s], hh, uzh, 0, 0, 0);
      uzh = __builtin_amdgcn_mfma_f32_16x16x32_bf16(afl[0][s], hl, uzh, 0, 0, 0);
      urw = __builtin_amdgcn_mfma_f32_16x16x32_bf16(afw[1][s], Mc[s], urw, 0, 0, 0);
      urh = __builtin_amdgcn_mfma_f32_16x16x32_bf16(afl[1][s], hh, urh, 0, 0, 0);
      urh = __builtin_amdgcn_mfma_f32_16x16x32_bf16(afl[1][s], hl, urh, 0, 0, 0);
    }
    f32x4 zv, rv;
#pragma unroll
    for (int r = 0; r < 4; ++r) {
      zv[r] = sigm(uzw[r] + uzh[r] + bzv[r]);
      rv[r] = sigm(urw[r] + urh[r] + brv[r]);
    }
    {
      u16x4 phi, plo;
#pragma unroll
      for (int r = 0; r < 4; ++r) {
        float p = hv[r] * rv[r];
        u16 hi = f2b(p); phi[r] = hi; plo[r] = f2b(p - b2f(hi));
      }
      *(u16x4*)&rhi[lm * 72 + cb] = phi;
      *(u16x4*)&rlo[lm * 72 + cb] = plo;
    }
    lds_barrier();                     // h*r visible; all reads of h done (LDS-only sync:
                                       // M-prefetch vmcnt deliberately left in flight)
    f32x4 uhw, uhh;
#pragma unroll
    for (int r = 0; r < 4; ++r) { uhw[r] = 0.f; uhh[r] = 0.f; }
#pragma unroll
    for (int s = 0; s < 2; ++s) {
      s16x8 rh = *(const s16x8*)&rhi[lm * 72 + 32 * s + q * 8];
      s16x8 rl = *(const s16x8*)&rlo[lm * 72 + 32 * s + q * 8];
      uhw = __builtin_amdgcn_mfma_f32_16x16x32_bf16(afw[2][s], Mc[s], uhw, 0, 0, 0);
      uhh = __builtin_amdgcn_mfma_f32_16x16x32_bf16(afl[2][s], rh, uhh, 0, 0, 0);
      uhh = __builtin_amdgcn_mfma_f32_16x16x32_bf16(afl[2][s], rl, uhh, 0, 0, 0);
    }
    {
      u16x4 phi, plo;
#pragma unroll
      for (int r = 0; r < 4; ++r) {
        float th = tanh_f(uhw[r] + uhh[r] + bhv[r]);
        float hn = zv[r] * hv[r] + (1.f - zv[r]) * th;
        hv[r] = hn;
        u16 hi = f2b(hn); phi[r] = hi; plo[r] = f2b(hn - b2f(hi));
      }
      *(u16x4*)&hhi[lm * 72 + cb] = phi;
      *(u16x4*)&hlo[lm * 72 + cb] = plo;
    }
    lds_barrier();                     // h_{t+1} visible; r-buffer reads done
  }
#pragma unroll
  for (int r = 0; r < 4; ++r)
    out[(size_t)(nb0 + lm) * 64 + cb + r] = hv[r];
}

extern "C" void kernel_launch(void* const* d_in, const int* in_sizes, int n_in,
                              void* d_out, int out_size, void* d_ws, size_t ws_size,
                              hipStream_t stream) {
  const float* x   = (const float*)d_in[0];
  const float* adj = (const float*)d_in[1];
  const float* fcw = (const float*)d_in[2];
  const float* fcb = (const float*)d_in[3];
  const float* Wz  = (const float*)d_in[4];
  const float* Wr  = (const float*)d_in[5];
  const float* Wh  = (const float*)d_in[6];
  const float* Lz  = (const float*)d_in[7];
  const float* Lr  = (const float*)d_in[8];
  const float* Lh  = (const float*)d_in[9];
  const float* bz  = (const float*)d_in[10];
  const float* br  = (const float*)d_in[11];
  const float* bh  = (const float*)d_in[12];
  char* ws = (char*)d_ws;
  // ws layout (bytes):
  u8*  xht  = (u8*)(ws);                           // [3072][4096] fp8: 12,582,912
  u8*  adj8 = (u8*)(ws + (size_t)12582912);        // [4096][4096] fp8: 16,777,216
  u16* Mm   = (u16*)(ws + (size_t)29360128);       // [4096][3072] bf16: 25,165,824
  u16* wct  = (u16*)(ws + (size_t)54525952);       // 24 KB
  u16* lbt  = (u16*)(ws + (size_t)54550528);       // 24 KB
  float* outp = (float*)d_out;

  hipLaunchKernelGGL(kpre, dim3(5683), dim3(256), 0, stream,
                     adj, adj8, fcw, fcb, x, xht, Wz, Wr, Wh, Lz, Lr, Lh, wct, lbt);
  hipLaunchKernelGGL(k2, dim3(16, 32), dim3(256), 0, stream, adj8, xht, Mm);
  hipLaunchKernelGGL(k3, dim3(256), dim3(256), 0, stream, Mm, wct, lbt, bz, br, bh, outp);
}

// Round 4
// 259.273 us; speedup vs baseline: 1.1685x; 1.0156x over previous
//
#include <hip/hip_runtime.h>

typedef unsigned short u16;
typedef unsigned char u8;
typedef short s16x8 __attribute__((ext_vector_type(8)));
typedef unsigned short u16x4 __attribute__((ext_vector_type(4)));
typedef float f32x4 __attribute__((ext_vector_type(4)));
typedef int i32x4 __attribute__((ext_vector_type(4)));
typedef int i32x8 __attribute__((ext_vector_type(8)));

#define AS1 __attribute__((address_space(1)))
#define AS3 __attribute__((address_space(3)))

// async global->LDS, 16B per lane; LDS dest = wave-uniform base + lane*16
__device__ __forceinline__ void g2l16(const void* g, void* l) {
  __builtin_amdgcn_global_load_lds((const AS1 void*)g, (AS3 void*)l, 16, 0, 0);
}

__device__ __forceinline__ float b2f(u16 u) {
  union { unsigned int i; float f; } x; x.i = ((unsigned int)u) << 16; return x.f;
}
__device__ __forceinline__ u16 f2b(float f) {  // round-to-nearest-even
  unsigned int u = __builtin_bit_cast(unsigned int, f);
  return (u16)((u + 0x7fffu + ((u >> 16) & 1u)) >> 16);
}
__device__ __forceinline__ u8 f2e4m3(float v) {
  int p = __builtin_amdgcn_cvt_pk_fp8_f32(v, 0.f, 0, false);
  return (u8)(p & 0xff);
}
__device__ __forceinline__ float sigm(float x) { return 1.f / (1.f + __expf(-x)); }
__device__ __forceinline__ float tanh_f(float x) { return 2.f / (1.f + __expf(-2.f * x)) - 1.f; }

// dims: T=48 N=4096 F_IN=H1=F_OUT=64; TH = 3072

// ---------------- kpre: adj->fp8 + weight prep + k1 (XHT), one launch ----------------
// blocks [0,4096): adj fp32->fp8 e4m3 scaled x4096 (coalesced)
// blocks [4096,4144): wct;  [4144,4147): lbt;  [4147,5683): XHT tiles
__global__ __launch_bounds__(256) void kpre(
    const float* __restrict__ a, u8* __restrict__ ab,
    const float* __restrict__ fcw, const float* __restrict__ fcb,
    const float* __restrict__ x, u8* __restrict__ xht,
    const float* __restrict__ Wz, const float* __restrict__ Wr, const float* __restrict__ Wh,
    const float* __restrict__ Lz, const float* __restrict__ Lr, const float* __restrict__ Lh,
    u16* __restrict__ wct, u16* __restrict__ lbt) {
  int b = blockIdx.x, tid = threadIdx.x;
  if (b < 4096) {
    size_t idx = (size_t)b * 256 + tid;   // lane-contiguous float4 index
    const float4* src = (const float4*)a;
    unsigned int* dst = (unsigned int*)ab;
#pragma unroll
    for (int k = 0; k < 4; ++k) {
      float4 v = src[idx + (size_t)k * 1048576];
      unsigned int p = __builtin_amdgcn_cvt_pk_fp8_f32(v.x * 4096.f, v.y * 4096.f, 0, false);
      p = __builtin_amdgcn_cvt_pk_fp8_f32(v.z * 4096.f, v.w * 4096.f, p, true);
      dst[idx + (size_t)k * 1048576] = p;
    }
    return;
  }
  if (b < 4144) {
    int idx = (b - 4096) * 256 + tid;  // 0..12287
    int c_cat = idx >> 6, hh = idx & 63;
    int g = c_cat >> 6, c = c_cat & 63;
    const float* W = (g == 0) ? Wz : (g == 1) ? Wr : Wh;
    const float* L = (g == 0) ? Lz : (g == 1) ? Lr : Lh;
    float acc = 0.f;
    for (int m = 0; m < 64; ++m) acc += W[hh * 64 + m] * L[m * 64 + c];
    wct[c_cat * 64 + hh] = f2b(acc);
    return;
  }
  if (b < 4147) {
    int g = b - 4144;
    const float* L = (g == 0) ? Lz : (g == 1) ? Lr : Lh;
    for (int i = 0; i < 16; ++i) {
      int idx = tid * 16 + i; int c = idx >> 6, hh = idx & 63;
      lbt[g * 4096 + c * 64 + hh] = f2b(L[(64 + hh) * 64 + c]);
    }
    return;
  }
  // ---- XHT part: kb in [0,1536): t = kb>>5, n0 = (kb&31)*128 ----
  int kb = b - 4147;
  int t = kb >> 5, n0 = (kb & 31) * 128;
  __shared__ __align__(16) u16 xs[128 * 72];   // padded: 2-way banks
  __shared__ __align__(16) u16 fw[64 * 72];
  __shared__ __align__(16) u8 xh8[64 * 128];   // [h][node]
  __shared__ float fb[64];
  int w = tid >> 6, l = tid & 63;
#pragma unroll
  for (int i = 0; i < 16; ++i) {       // fw[h][f] = fc_w[f][h], coalesced fp32 reads
    int idx = tid + i * 256;
    int h = idx & 63, f = idx >> 6;
    fw[h * 72 + f] = f2b(fcw[f * 64 + h]);
  }
  const float4* xg = (const float4*)(x + ((size_t)t * 4096 + n0) * 64);
#pragma unroll
  for (int i = 0; i < 8; ++i) {
    int f = tid + i * 256;             // lane-contiguous float4 index
    float4 v = xg[f];
    u16x4 p; p[0] = f2b(v.x); p[1] = f2b(v.y); p[2] = f2b(v.z); p[3] = f2b(v.w);
    *(u16x4*)&xs[(f >> 4) * 72 + (f & 15) * 4] = p;
  }
  if (tid < 64) fb[tid] = fcb[tid];
  __syncthreads();

  int lm = l & 15, q = l >> 4;
  f32x4 acc[4][2];
#pragma unroll
  for (int i = 0; i < 4; ++i)
#pragma unroll
    for (int j = 0; j < 2; ++j)
#pragma unroll
      for (int r = 0; r < 4; ++r) acc[i][j][r] = 0.f;
#pragma unroll
  for (int s = 0; s < 2; ++s) {
    s16x8 af[4], bf[2];
#pragma unroll
    for (int i = 0; i < 4; ++i) af[i] = *(const s16x8*)&fw[(16 * i + lm) * 72 + 32 * s + q * 8];
#pragma unroll
    for (int j = 0; j < 2; ++j) bf[j] = *(const s16x8*)&xs[(32 * w + 16 * j + lm) * 72 + 32 * s + q * 8];
#pragma unroll
    for (int i = 0; i < 4; ++i)
#pragma unroll
      for (int j = 0; j < 2; ++j)
        acc[i][j] = __builtin_amdgcn_mfma_f32_16x16x32_bf16(af[i], bf[j], acc[i][j], 0, 0, 0);
  }
#pragma unroll
  for (int i = 0; i < 4; ++i)
#pragma unroll
    for (int j = 0; j < 2; ++j) {
      int node = 32 * w + 16 * j + lm;
      int h0 = 16 * i + q * 4;
#pragma unroll
      for (int r = 0; r < 4; ++r) {
        float v = acc[i][j][r] + fb[h0 + r];
        xh8[(h0 + r) * 128 + node] = f2e4m3(v > 0.f ? v : 0.f);
      }
    }
  __syncthreads();
  {
    int h = tid >> 2, seg = tid & 3;   // 32 bytes per thread
    u8* dst = xht + (size_t)(t * 64 + h) * 4096 + n0 + seg * 32;
    const u8* src = &xh8[h * 128 + seg * 32];
    *(i32x4*)dst = *(const i32x4*)src;
    *(i32x4*)(dst + 16) = *(const i32x4*)(src + 16);
  }
}

// ---------------- k2: M = adj8 @ XH8, MX fp8 K=128, 128x192 tile ----------------
// Round-0 staging (both operands g2l16, coalesced, rotation swizzle) but
// DOUBLE-BUFFERED (2 x 40KB LDS) with ONE barrier per K-step: STAGE(next)
// is issued before compute on the current buffer, so the compiler's
// vmcnt(0)+s_barrier drain lands after ~1.9k cycles of ds_read+MFMA and
// the staged loads have already returned. 2 blocks/CU (160KB LDS exactly).
__global__ __launch_bounds__(256) void k2(
    const u8* __restrict__ A, const u8* __restrict__ B, u16* __restrict__ M) {
  __shared__ __align__(16) u8 sh[81920];   // 2 x (A 16KB + B 24KB)
  int tid = threadIdx.x, w = tid >> 6, l = tid & 63;
  int nt = blockIdx.x, mt = blockIdx.y;
  const u8* Ab = A + (size_t)mt * 128 * 4096;
  const u8* Bb = B + (size_t)nt * 192 * 4096;
  int lm = l & 15, q = l >> 4;
  int wm = w >> 1, wn = w & 1;
  int srow = l >> 3, scol = l & 7;
  f32x4 acc[4][6];
#pragma unroll
  for (int i = 0; i < 4; ++i)
#pragma unroll
    for (int j = 0; j < 6; ++j)
#pragma unroll
      for (int r = 0; r < 4; ++r) acc[i][j][r] = 0.f;

#define STAGE(bsel, kk)                                                       \
  do {                                                                        \
    u8* As_ = sh + (bsel) * 40960;                                            \
    u8* Bs_ = As_ + 16384;                                                    \
    _Pragma("unroll") for (int j = 0; j < 4; ++j) {   /* A: 32 rows/wave */   \
      int r0 = 32 * w + 8 * j;                                                \
      int row = r0 + srow;                                                    \
      int c = (scol - row) & 7;                                               \
      g2l16(Ab + (size_t)row * 4096 + (kk) + c * 16, As_ + r0 * 128);         \
    }                                                                         \
    _Pragma("unroll") for (int j = 0; j < 6; ++j) {   /* B: 48 rows/wave */   \
      int r0 = 48 * w + 8 * j;                                                \
      int row = r0 + srow;                                                    \
      int c = (scol - row) & 7;                                               \
      g2l16(Bb + (size_t)row * 4096 + (kk) + c * 16, Bs_ + r0 * 128);         \
    }                                                                         \
  } while (0)

  STAGE(0, 0);
  __syncthreads();                     // buf0 ready

  for (int it = 0; it < 32; ++it) {
    int k0b = it * 128;
    int cur = it & 1;
    if (it < 31) STAGE(cur ^ 1, k0b + 128);   // prefetch next K-tile into other buffer
    const u8* As = sh + cur * 40960;
    const u8* Bs = As + 16384;
    i32x8 a8[4];
#pragma unroll
    for (int i = 0; i < 4; ++i) {
      int ra = 64 * wm + 16 * i + lm;
      int p0 = (2 * q + ra) & 7, p1 = (2 * q + 1 + ra) & 7;
      i32x4 lo = *(const i32x4*)&As[ra * 128 + p0 * 16];
      i32x4 hi = *(const i32x4*)&As[ra * 128 + p1 * 16];
      a8[i] = __builtin_shufflevector(lo, hi, 0, 1, 2, 3, 4, 5, 6, 7);
    }
#pragma unroll
    for (int j = 0; j < 6; ++j) {
      int rb = 96 * wn + 16 * j + lm;
      int q0 = (2 * q + rb) & 7, q1 = (2 * q + 1 + rb) & 7;
      i32x4 lo2 = *(const i32x4*)&Bs[rb * 128 + q0 * 16];
      i32x4 hi2 = *(const i32x4*)&Bs[rb * 128 + q1 * 16];
      i32x8 b8 = __builtin_shufflevector(lo2, hi2, 0, 1, 2, 3, 4, 5, 6, 7);
#pragma unroll
      for (int i = 0; i < 4; ++i)
        acc[i][j] = __builtin_amdgcn_mfma_scale_f32_16x16x128_f8f6f4(
            a8[i], b8, acc[i][j], 0, 0, 0, 127, 0, 127);  // fmt=fp8, scale=2^0
    }
    __syncthreads();   // one barrier/iter: drains next-buf writes AND cur-buf reads
  }
#undef STAGE

  // epilogue: 2-pass transpose through LDS. tb = [64][200] u16 (25.6KB)
  u16* tb = (u16*)sh;
  const float sc = 1.f / 4096.f;
#pragma unroll
  for (int p = 0; p < 2; ++p) {
    if (p) __syncthreads();            // pass-0 LDS reads done before overwrite
    if (wm == p) {
#pragma unroll
      for (int i = 0; i < 4; ++i)
#pragma unroll
        for (int j = 0; j < 6; ++j)
#pragma unroll
          for (int r = 0; r < 4; ++r)
            tb[(16 * i + 4 * q + r) * 200 + 96 * wn + 16 * j + lm] = f2b(acc[i][j][r] * sc);
    }
    __syncthreads();
    int row = tid >> 2, seg = tid & 3;   // 64 rows x 384B; 96B (48 u16) per thread
    u16* dst = M + (size_t)(mt * 128 + p * 64 + row) * 3072 + nt * 192 + seg * 48;
    const u16* src = &tb[row * 200 + seg * 48];
#pragma unroll
    for (int v = 0; v < 6; ++v)
      *(i32x4*)(dst + 8 * v) = *(const i32x4*)(src + 8 * v);
  }
}

// ---------------- k3: GRU scan; weights in regs, 2 barriers/step, split acc chains ----------------
// (round-0 exact version: __syncthreads; the lds_barrier asm variant cost ~+2.5us)
__global__ __launch_bounds__(256) void k3(
    const u16* __restrict__ M, const u16* __restrict__ wct, const u16* __restrict__ lbt,
    const float* __restrict__ bz, const float* __restrict__ br, const float* __restrict__ bh,
    float* __restrict__ out) {
  __shared__ __align__(16) u16 hhi[16 * 72], hlo[16 * 72];
  __shared__ __align__(16) u16 rhi[16 * 72], rlo[16 * 72];
  int tid = threadIdx.x, w = tid >> 6, l = tid & 63;
  int nb0 = blockIdx.x * 16;
  int lm = l & 15, q = l >> 4;
  int cb = 16 * w + q * 4;
  s16x8 afw[3][2], afl[3][2];
#pragma unroll
  for (int g = 0; g < 3; ++g)
#pragma unroll
    for (int s = 0; s < 2; ++s) {
      afw[g][s] = *(const s16x8*)&wct[(size_t)(g * 64 + 16 * w + lm) * 64 + 32 * s + q * 8];
      afl[g][s] = *(const s16x8*)&lbt[(size_t)(g * 64 + 16 * w + lm) * 64 + 32 * s + q * 8];
    }
  for (int i = tid; i < 16 * 72; i += 256) { hhi[i] = 0; hlo[i] = 0; }
  f32x4 bzv, brv, bhv, hv;
#pragma unroll
  for (int r = 0; r < 4; ++r) {
    bzv[r] = bz[cb + r]; brv[r] = br[cb + r]; bhv[r] = bh[cb + r]; hv[r] = 0.f;
  }
  __syncthreads();

  const u16* Mrow = M + (size_t)(nb0 + lm) * 3072;
  s16x8 Mn[2];
  Mn[0] = *(const s16x8*)&Mrow[q * 8];
  Mn[1] = *(const s16x8*)&Mrow[32 + q * 8];

  for (int t = 0; t < 48; ++t) {
    s16x8 Mc[2] = {Mn[0], Mn[1]};
    if (t < 47) {
      Mn[0] = *(const s16x8*)&Mrow[(t + 1) * 64 + q * 8];
      Mn[1] = *(const s16x8*)&Mrow[(t + 1) * 64 + 32 + q * 8];
    }
    f32x4 uzw, uzh, urw, urh;
#pragma unroll
    for (int r = 0; r < 4; ++r) { uzw[r] = 0.f; uzh[r] = 0.f; urw[r] = 0.f; urh[r] = 0.f; }
#pragma unroll
    for (int s = 0; s < 2; ++s) {
      s16x8 hh = *(const s16x8*)&hhi[lm * 72 + 32 * s + q * 8];
      s16x8 hl = *(const s16x8*)&hlo[lm * 72 + 32 * s + q * 8];
      uzw = __builtin_amdgcn_mfma_f32_16x16x32_bf16(afw[0][s], Mc[s], uzw, 0, 0, 0);
      uzh = __builtin_amdgcn_mfma_f32_16x16x32_bf16(afl[0][s], hh, uzh, 0, 0, 0);
      uzh = __builtin_amdgcn_mfma_f32_16x16x32_bf16(afl[0][s], hl, uzh, 0, 0, 0);
      urw = __builtin_amdgcn_mfma_f32_16x16x32_bf16(afw[1][s], Mc[s], urw, 0, 0, 0);
      urh = __builtin_amdgcn_mfma_f32_16x16x32_bf16(afl[1][s], hh, urh, 0, 0, 0);
      urh = __builtin_amdgcn_mfma_f32_16x16x32_bf16(afl[1][s], hl, urh, 0, 0, 0);
    }
    f32x4 zv, rv;
#pragma unroll
    for (int r = 0; r < 4; ++r) {
      zv[r] = sigm(uzw[r] + uzh[r] + bzv[r]);
      rv[r] = sigm(urw[r] + urh[r] + brv[r]);
    }
    {
      u16x4 phi, plo;
#pragma unroll
      for (int r = 0; r < 4; ++r) {
        float p = hv[r] * rv[r];
        u16 hi = f2b(p); phi[r] = hi; plo[r] = f2b(p - b2f(hi));
      }
      *(u16x4*)&rhi[lm * 72 + cb] = phi;
      *(u16x4*)&rlo[lm * 72 + cb] = plo;
    }
    __syncthreads();                   // h*r visible; all reads of h done
    f32x4 uhw, uhh;
#pragma unroll
    for (int r = 0; r < 4; ++r) { uhw[r] = 0.f; uhh[r] = 0.f; }
#pragma unroll
    for (int s = 0; s < 2; ++s) {
      s16x8 rh = *(const s16x8*)&rhi[lm * 72 + 32 * s + q * 8];
      s16x8 rl = *(const s16x8*)&rlo[lm * 72 + 32 * s + q * 8];
      uhw = __builtin_amdgcn_mfma_f32_16x16x32_bf16(afw[2][s], Mc[s], uhw, 0, 0, 0);
      uhh = __builtin_amdgcn_mfma_f32_16x16x32_bf16(afl[2][s], rh, uhh, 0, 0, 0);
      uhh = __builtin_amdgcn_mfma_f32_16x16x32_bf16(afl[2][s], rl, uhh, 0, 0, 0);
    }
    {
      u16x4 phi, plo;
#pragma unroll
      for (int r = 0; r < 4; ++r) {
        float th = tanh_f(uhw[r] + uhh[r] + bhv[r]);
        float hn = zv[r] * hv[r] + (1.f - zv[r]) * th;
        hv[r] = hn;
        u16 hi = f2b(hn); phi[r] = hi; plo[r] = f2b(hn - b2f(hi));
      }
      *(u16x4*)&hhi[lm * 72 + cb] = phi;
      *(u16x4*)&hlo[lm * 72 + cb] = plo;
    }
    __syncthreads();                   // h_{t+1} visible; r-buffer reads done
  }
#pragma unroll
  for (int r = 0; r < 4; ++r)
    out[(size_t)(nb0 + lm) * 64 + cb + r] = hv[r];
}

extern "C" void kernel_launch(void* const* d_in, const int* in_sizes, int n_in,
                              void* d_out, int out_size, void* d_ws, size_t ws_size,
                              hipStream_t stream) {
  const float* x   = (const float*)d_in[0];
  const float* adj = (const float*)d_in[1];
  const float* fcw = (const float*)d_in[2];
  const float* fcb = (const float*)d_in[3];
  const float* Wz  = (const float*)d_in[4];
  const float* Wr  = (const float*)d_in[5];
  const float* Wh  = (const float*)d_in[6];
  const float* Lz  = (const float*)d_in[7];
  const float* Lr  = (const float*)d_in[8];
  const float* Lh  = (const float*)d_in[9];
  const float* bz  = (const float*)d_in[10];
  const float* br  = (const float*)d_in[11];
  const float* bh  = (const float*)d_in[12];
  char* ws = (char*)d_ws;
  // ws layout (bytes):
  u8*  xht  = (u8*)(ws);                           // [3072][4096] fp8: 12,582,912
  u8*  adj8 = (u8*)(ws + (size_t)12582912);        // [4096][4096] fp8: 16,777,216
  u16* Mm   = (u16*)(ws + (size_t)29360128);       // [4096][3072] bf16: 25,165,824
  u16* wct  = (u16*)(ws + (size_t)54525952);       // 24 KB
  u16* lbt  = (u16*)(ws + (size_t)54550528);       // 24 KB
  float* outp = (float*)d_out;

  hipLaunchKernelGGL(kpre, dim3(5683), dim3(256), 0, stream,
                     adj, adj8, fcw, fcb, x, xht, Wz, Wr, Wh, Lz, Lr, Lh, wct, lbt);
  hipLaunchKernelGGL(k2, dim3(16, 32), dim3(256), 0, stream, adj8, xht, Mm);
  hipLaunchKernelGGL(k3, dim3(256), dim3(256), 0, stream, Mm, wct, lbt, bz, br, bh, outp);
}

// Round 5
// 258.315 us; speedup vs baseline: 1.1729x; 1.0037x over previous
//
#include <hip/hip_runtime.h>

typedef unsigned short u16;
typedef unsigned char u8;
typedef short s16x8 __attribute__((ext_vector_type(8)));
typedef unsigned short u16x4 __attribute__((ext_vector_type(4)));
typedef float f32x4 __attribute__((ext_vector_type(4)));
typedef int i32x4 __attribute__((ext_vector_type(4)));
typedef int i32x8 __attribute__((ext_vector_type(8)));

#define AS1 __attribute__((address_space(1)))
#define AS3 __attribute__((address_space(3)))

// async global->LDS, 16B per lane; LDS dest = wave-uniform base + lane*16
__device__ __forceinline__ void g2l16(const void* g, void* l) {
  __builtin_amdgcn_global_load_lds((const AS1 void*)g, (AS3 void*)l, 16, 0, 0);
}

__device__ __forceinline__ float b2f(u16 u) {
  union { unsigned int i; float f; } x; x.i = ((unsigned int)u) << 16; return x.f;
}
__device__ __forceinline__ u16 f2b(float f) {  // round-to-nearest-even
  unsigned int u = __builtin_bit_cast(unsigned int, f);
  return (u16)((u + 0x7fffu + ((u >> 16) & 1u)) >> 16);
}
__device__ __forceinline__ u8 f2e4m3(float v) {
  int p = __builtin_amdgcn_cvt_pk_fp8_f32(v, 0.f, 0, false);
  return (u8)(p & 0xff);
}
__device__ __forceinline__ float sigm(float x) { return 1.f / (1.f + __expf(-x)); }
__device__ __forceinline__ float tanh_f(float x) { return 2.f / (1.f + __expf(-2.f * x)) - 1.f; }

// dims: T=48 N=4096 F_IN=H1=F_OUT=64; TH = 3072

// ---------------- kpre: adj->fp8 + weight prep + k1 (XHT), one launch ----------------
// blocks [0,4096): adj fp32->fp8 e4m3 scaled x4096 (coalesced)
// blocks [4096,4144): wct;  [4144,4147): lbt;  [4147,5683): XHT tiles
__global__ __launch_bounds__(256) void kpre(
    const float* __restrict__ a, u8* __restrict__ ab,
    const float* __restrict__ fcw, const float* __restrict__ fcb,
    const float* __restrict__ x, u8* __restrict__ xht,
    const float* __restrict__ Wz, const float* __restrict__ Wr, const float* __restrict__ Wh,
    const float* __restrict__ Lz, const float* __restrict__ Lr, const float* __restrict__ Lh,
    u16* __restrict__ wct, u16* __restrict__ lbt) {
  int b = blockIdx.x, tid = threadIdx.x;
  if (b < 4096) {
    size_t idx = (size_t)b * 256 + tid;   // lane-contiguous float4 index
    const float4* src = (const float4*)a;
    unsigned int* dst = (unsigned int*)ab;
#pragma unroll
    for (int k = 0; k < 4; ++k) {
      float4 v = src[idx + (size_t)k * 1048576];
      unsigned int p = __builtin_amdgcn_cvt_pk_fp8_f32(v.x * 4096.f, v.y * 4096.f, 0, false);
      p = __builtin_amdgcn_cvt_pk_fp8_f32(v.z * 4096.f, v.w * 4096.f, p, true);
      dst[idx + (size_t)k * 1048576] = p;
    }
    return;
  }
  if (b < 4144) {
    int idx = (b - 4096) * 256 + tid;  // 0..12287
    int c_cat = idx >> 6, hh = idx & 63;
    int g = c_cat >> 6, c = c_cat & 63;
    const float* W = (g == 0) ? Wz : (g == 1) ? Wr : Wh;
    const float* L = (g == 0) ? Lz : (g == 1) ? Lr : Lh;
    float acc = 0.f;
    for (int m = 0; m < 64; ++m) acc += W[hh * 64 + m] * L[m * 64 + c];
    wct[c_cat * 64 + hh] = f2b(acc);
    return;
  }
  if (b < 4147) {
    int g = b - 4144;
    const float* L = (g == 0) ? Lz : (g == 1) ? Lr : Lh;
    for (int i = 0; i < 16; ++i) {
      int idx = tid * 16 + i; int c = idx >> 6, hh = idx & 63;
      lbt[g * 4096 + c * 64 + hh] = f2b(L[(64 + hh) * 64 + c]);
    }
    return;
  }
  // ---- XHT part: kb in [0,1536): t = kb>>5, n0 = (kb&31)*128 ----
  int kb = b - 4147;
  int t = kb >> 5, n0 = (kb & 31) * 128;
  __shared__ __align__(16) u16 xs[128 * 72];   // padded: 2-way banks
  __shared__ __align__(16) u16 fw[64 * 72];
  __shared__ __align__(16) u8 xh8[64 * 128];   // [h][node]
  __shared__ float fb[64];
  int w = tid >> 6, l = tid & 63;
#pragma unroll
  for (int i = 0; i < 16; ++i) {       // fw[h][f] = fc_w[f][h], coalesced fp32 reads
    int idx = tid + i * 256;
    int h = idx & 63, f = idx >> 6;
    fw[h * 72 + f] = f2b(fcw[f * 64 + h]);
  }
  const float4* xg = (const float4*)(x + ((size_t)t * 4096 + n0) * 64);
#pragma unroll
  for (int i = 0; i < 8; ++i) {
    int f = tid + i * 256;             // lane-contiguous float4 index
    float4 v = xg[f];
    u16x4 p; p[0] = f2b(v.x); p[1] = f2b(v.y); p[2] = f2b(v.z); p[3] = f2b(v.w);
    *(u16x4*)&xs[(f >> 4) * 72 + (f & 15) * 4] = p;
  }
  if (tid < 64) fb[tid] = fcb[tid];
  __syncthreads();

  int lm = l & 15, q = l >> 4;
  f32x4 acc[4][2];
#pragma unroll
  for (int i = 0; i < 4; ++i)
#pragma unroll
    for (int j = 0; j < 2; ++j)
#pragma unroll
      for (int r = 0; r < 4; ++r) acc[i][j][r] = 0.f;
#pragma unroll
  for (int s = 0; s < 2; ++s) {
    s16x8 af[4], bf[2];
#pragma unroll
    for (int i = 0; i < 4; ++i) af[i] = *(const s16x8*)&fw[(16 * i + lm) * 72 + 32 * s + q * 8];
#pragma unroll
    for (int j = 0; j < 2; ++j) bf[j] = *(const s16x8*)&xs[(32 * w + 16 * j + lm) * 72 + 32 * s + q * 8];
#pragma unroll
    for (int i = 0; i < 4; ++i)
#pragma unroll
      for (int j = 0; j < 2; ++j)
        acc[i][j] = __builtin_amdgcn_mfma_f32_16x16x32_bf16(af[i], bf[j], acc[i][j], 0, 0, 0);
  }
#pragma unroll
  for (int i = 0; i < 4; ++i)
#pragma unroll
    for (int j = 0; j < 2; ++j) {
      int node = 32 * w + 16 * j + lm;
      int h0 = 16 * i + q * 4;
#pragma unroll
      for (int r = 0; r < 4; ++r) {
        float v = acc[i][j][r] + fb[h0 + r];
        xh8[(h0 + r) * 128 + node] = f2e4m3(v > 0.f ? v : 0.f);
      }
    }
  __syncthreads();
  {
    int h = tid >> 2, seg = tid & 3;   // 32 bytes per thread
    u8* dst = xht + (size_t)(t * 64 + h) * 4096 + n0 + seg * 32;
    const u8* src = &xh8[h * 128 + seg * 32];
    *(i32x4*)dst = *(const i32x4*)src;
    *(i32x4*)(dst + 16) = *(const i32x4*)(src + 16);
  }
}

// ---------------- k2: M = adj8 @ XH8, MX fp8 K=128, 128x192 tile ----------------
// Double-buffered (2 x 40KB) with COUNTED vmcnt + raw s_barrier (T4): the
// stage for tile t+1 is issued in iter t and stays in flight across BOTH
// barriers; iter t+1 waits vmcnt(10) (its own 10 just-issued loads may
// remain outstanding), never vmcnt(0) in the main loop. Race audit:
//   RAW buf(t+1): vmcnt(10) retires the OLDER 10 loads (in-order), then
//     barrier-A -> all waves' stage(t+1) landed before any read.
//   WAR buf(t):  lgkmcnt(0)+barrier-B -> all ds_reads of buf(t) retired
//     before any wave issues STAGE(t+2) which overwrites it.
// T5: setprio(1) around the MFMA cluster. 2 blocks/CU (160KB LDS).
__global__ __launch_bounds__(256) void k2(
    const u8* __restrict__ A, const u8* __restrict__ B, u16* __restrict__ M) {
  __shared__ __align__(16) u8 sh[81920];   // 2 x (A 16KB + B 24KB)
  int tid = threadIdx.x, w = tid >> 6, l = tid & 63;
  int nt = blockIdx.x, mt = blockIdx.y;
  const u8* Ab = A + (size_t)mt * 128 * 4096;
  const u8* Bb = B + (size_t)nt * 192 * 4096;
  int lm = l & 15, q = l >> 4;
  int wm = w >> 1, wn = w & 1;
  int srow = l >> 3, scol = l & 7;
  f32x4 acc[4][6];
#pragma unroll
  for (int i = 0; i < 4; ++i)
#pragma unroll
    for (int j = 0; j < 6; ++j)
#pragma unroll
      for (int r = 0; r < 4; ++r) acc[i][j][r] = 0.f;

#define STAGE(bsel, kk)                                                       \
  do {                                                                        \
    u8* As_ = sh + (bsel) * 40960;                                            \
    u8* Bs_ = As_ + 16384;                                                    \
    _Pragma("unroll") for (int j = 0; j < 4; ++j) {   /* A: 32 rows/wave */   \
      int r0 = 32 * w + 8 * j;                                                \
      int row = r0 + srow;                                                    \
      int c = (scol - row) & 7;                                               \
      g2l16(Ab + (size_t)row * 4096 + (kk) + c * 16, As_ + r0 * 128);         \
    }                                                                         \
    _Pragma("unroll") for (int j = 0; j < 6; ++j) {   /* B: 48 rows/wave */   \
      int r0 = 48 * w + 8 * j;                                                \
      int row = r0 + srow;                                                    \
      int c = (scol - row) & 7;                                               \
      g2l16(Bb + (size_t)row * 4096 + (kk) + c * 16, Bs_ + r0 * 128);         \
    }                                                                         \
  } while (0)

  STAGE(0, 0);                         // 10 loads/wave in flight

  for (int it = 0; it < 32; ++it) {
    int k0b = it * 128;
    int cur = it & 1;
    if (it < 31) {
      STAGE(cur ^ 1, k0b + 128);       // prefetch tile t+1 (10 more loads)
      asm volatile("s_waitcnt vmcnt(10)" ::: "memory");  // tile t landed; t+1 in flight
    } else {
      asm volatile("s_waitcnt vmcnt(0)" ::: "memory");   // final tile: full drain
    }
    __builtin_amdgcn_s_barrier();      // barrier A: buf(cur) ready for all waves
    const u8* As = sh + cur * 40960;
    const u8* Bs = As + 16384;
    i32x8 a8[4];
#pragma unroll
    for (int i = 0; i < 4; ++i) {
      int ra = 64 * wm + 16 * i + lm;
      int p0 = (2 * q + ra) & 7, p1 = (2 * q + 1 + ra) & 7;
      i32x4 lo = *(const i32x4*)&As[ra * 128 + p0 * 16];
      i32x4 hi = *(const i32x4*)&As[ra * 128 + p1 * 16];
      a8[i] = __builtin_shufflevector(lo, hi, 0, 1, 2, 3, 4, 5, 6, 7);
    }
    __builtin_amdgcn_s_setprio(1);
#pragma unroll
    for (int j = 0; j < 6; ++j) {
      int rb = 96 * wn + 16 * j + lm;
      int q0 = (2 * q + rb) & 7, q1 = (2 * q + 1 + rb) & 7;
      i32x4 lo2 = *(const i32x4*)&Bs[rb * 128 + q0 * 16];
      i32x4 hi2 = *(const i32x4*)&Bs[rb * 128 + q1 * 16];
      i32x8 b8 = __builtin_shufflevector(lo2, hi2, 0, 1, 2, 3, 4, 5, 6, 7);
#pragma unroll
      for (int i = 0; i < 4; ++i)
        acc[i][j] = __builtin_amdgcn_mfma_scale_f32_16x16x128_f8f6f4(
            a8[i], b8, acc[i][j], 0, 0, 0, 127, 0, 127);  // fmt=fp8, scale=2^0
    }
    __builtin_amdgcn_s_setprio(0);
    asm volatile("s_waitcnt lgkmcnt(0)" ::: "memory");  // this wave's ds_reads retired
    __builtin_amdgcn_s_barrier();      // barrier B: buf(cur) safe to overwrite next iter
  }
#undef STAGE

  // epilogue: 2-pass transpose through LDS. tb = [64][200] u16 (25.6KB)
  u16* tb = (u16*)sh;
  const float sc = 1.f / 4096.f;
#pragma unroll
  for (int p = 0; p < 2; ++p) {
    if (p) __syncthreads();            // pass-0 LDS reads done before overwrite
    if (wm == p) {
#pragma unroll
      for (int i = 0; i < 4; ++i)
#pragma unroll
        for (int j = 0; j < 6; ++j)
#pragma unroll
          for (int r = 0; r < 4; ++r)
            tb[(16 * i + 4 * q + r) * 200 + 96 * wn + 16 * j + lm] = f2b(acc[i][j][r] * sc);
    }
    __syncthreads();
    int row = tid >> 2, seg = tid & 3;   // 64 rows x 384B; 96B (48 u16) per thread
    u16* dst = M + (size_t)(mt * 128 + p * 64 + row) * 3072 + nt * 192 + seg * 48;
    const u16* src = &tb[row * 200 + seg * 48];
#pragma unroll
    for (int v = 0; v < 6; ++v)
      *(i32x4*)(dst + 8 * v) = *(const i32x4*)(src + 8 * v);
  }
}

// ---------------- k3: GRU scan; weights in regs, 2 barriers/step, split acc chains ----------------
__global__ __launch_bounds__(256) void k3(
    const u16* __restrict__ M, const u16* __restrict__ wct, const u16* __restrict__ lbt,
    const float* __restrict__ bz, const float* __restrict__ br, const float* __restrict__ bh,
    float* __restrict__ out) {
  __shared__ __align__(16) u16 hhi[16 * 72], hlo[16 * 72];
  __shared__ __align__(16) u16 rhi[16 * 72], rlo[16 * 72];
  int tid = threadIdx.x, w = tid >> 6, l = tid & 63;
  int nb0 = blockIdx.x * 16;
  int lm = l & 15, q = l >> 4;
  int cb = 16 * w + q * 4;
  s16x8 afw[3][2], afl[3][2];
#pragma unroll
  for (int g = 0; g < 3; ++g)
#pragma unroll
    for (int s = 0; s < 2; ++s) {
      afw[g][s] = *(const s16x8*)&wct[(size_t)(g * 64 + 16 * w + lm) * 64 + 32 * s + q * 8];
      afl[g][s] = *(const s16x8*)&lbt[(size_t)(g * 64 + 16 * w + lm) * 64 + 32 * s + q * 8];
    }
  for (int i = tid; i < 16 * 72; i += 256) { hhi[i] = 0; hlo[i] = 0; }
  f32x4 bzv, brv, bhv, hv;
#pragma unroll
  for (int r = 0; r < 4; ++r) {
    bzv[r] = bz[cb + r]; brv[r] = br[cb + r]; bhv[r] = bh[cb + r]; hv[r] = 0.f;
  }
  __syncthreads();

  const u16* Mrow = M + (size_t)(nb0 + lm) * 3072;
  s16x8 Mn[2];
  Mn[0] = *(const s16x8*)&Mrow[q * 8];
  Mn[1] = *(const s16x8*)&Mrow[32 + q * 8];

  for (int t = 0; t < 48; ++t) {
    s16x8 Mc[2] = {Mn[0], Mn[1]};
    if (t < 47) {
      Mn[0] = *(const s16x8*)&Mrow[(t + 1) * 64 + q * 8];
      Mn[1] = *(const s16x8*)&Mrow[(t + 1) * 64 + 32 + q * 8];
    }
    f32x4 uzw, uzh, urw, urh;
#pragma unroll
    for (int r = 0; r < 4; ++r) { uzw[r] = 0.f; uzh[r] = 0.f; urw[r] = 0.f; urh[r] = 0.f; }
#pragma unroll
    for (int s = 0; s < 2; ++s) {
      s16x8 hh = *(const s16x8*)&hhi[lm * 72 + 32 * s + q * 8];
      s16x8 hl = *(const s16x8*)&hlo[lm * 72 + 32 * s + q * 8];
      uzw = __builtin_amdgcn_mfma_f32_16x16x32_bf16(afw[0][s], Mc[s], uzw, 0, 0, 0);
      uzh = __builtin_amdgcn_mfma_f32_16x16x32_bf16(afl[0][s], hh, uzh, 0, 0, 0);
      uzh = __builtin_amdgcn_mfma_f32_16x16x32_bf16(afl[0][s], hl, uzh, 0, 0, 0);
      urw = __builtin_amdgcn_mfma_f32_16x16x32_bf16(afw[1][s], Mc[s], urw, 0, 0, 0);
      urh = __builtin_amdgcn_mfma_f32_16x16x32_bf16(afl[1][s], hh, urh, 0, 0, 0);
      urh = __builtin_amdgcn_mfma_f32_16x16x32_bf16(afl[1][s], hl, urh, 0, 0, 0);
    }
    f32x4 zv, rv;
#pragma unroll
    for (int r = 0; r < 4; ++r) {
      zv[r] = sigm(uzw[r] + uzh[r] + bzv[r]);
      rv[r] = sigm(urw[r] + urh[r] + brv[r]);
    }
    {
      u16x4 phi, plo;
#pragma unroll
      for (int r = 0; r < 4; ++r) {
        float p = hv[r] * rv[r];
        u16 hi = f2b(p); phi[r] = hi; plo[r] = f2b(p - b2f(hi));
      }
      *(u16x4*)&rhi[lm * 72 + cb] = phi;
      *(u16x4*)&rlo[lm * 72 + cb] = plo;
    }
    __syncthreads();                   // h*r visible; all reads of h done
    f32x4 uhw, uhh;
#pragma unroll
    for (int r = 0; r < 4; ++r) { uhw[r] = 0.f; uhh[r] = 0.f; }
#pragma unroll
    for (int s = 0; s < 2; ++s) {
      s16x8 rh = *(const s16x8*)&rhi[lm * 72 + 32 * s + q * 8];
      s16x8 rl = *(const s16x8*)&rlo[lm * 72 + 32 * s + q * 8];
      uhw = __builtin_amdgcn_mfma_f32_16x16x32_bf16(afw[2][s], Mc[s], uhw, 0, 0, 0);
      uhh = __builtin_amdgcn_mfma_f32_16x16x32_bf16(afl[2][s], rh, uhh, 0, 0, 0);
      uhh = __builtin_amdgcn_mfma_f32_16x16x32_bf16(afl[2][s], rl, uhh, 0, 0, 0);
    }
    {
      u16x4 phi, plo;
#pragma unroll
      for (int r = 0; r < 4; ++r) {
        float th = tanh_f(uhw[r] + uhh[r] + bhv[r]);
        float hn = zv[r] * hv[r] + (1.f - zv[r]) * th;
        hv[r] = hn;
        u16 hi = f2b(hn); phi[r] = hi; plo[r] = f2b(hn - b2f(hi));
      }
      *(u16x4*)&hhi[lm * 72 + cb] = phi;
      *(u16x4*)&hlo[lm * 72 + cb] = plo;
    }
    __syncthreads();                   // h_{t+1} visible; r-buffer reads done
  }
#pragma unroll
  for (int r = 0; r < 4; ++r)
    out[(size_t)(nb0 + lm) * 64 + cb + r] = hv[r];
}

extern "C" void kernel_launch(void* const* d_in, const int* in_sizes, int n_in,
                              void* d_out, int out_size, void* d_ws, size_t ws_size,
                              hipStream_t stream) {
  const float* x   = (const float*)d_in[0];
  const float* adj = (const float*)d_in[1];
  const float* fcw = (const float*)d_in[2];
  const float* fcb = (const float*)d_in[3];
  const float* Wz  = (const float*)d_in[4];
  const float* Wr  = (const float*)d_in[5];
  const float* Wh  = (const float*)d_in[6];
  const float* Lz  = (const float*)d_in[7];
  const float* Lr  = (const float*)d_in[8];
  const float* Lh  = (const float*)d_in[9];
  const float* bz  = (const float*)d_in[10];
  const float* br  = (const float*)d_in[11];
  const float* bh  = (const float*)d_in[12];
  char* ws = (char*)d_ws;
  // ws layout (bytes):
  u8*  xht  = (u8*)(ws);                           // [3072][4096] fp8: 12,582,912
  u8*  adj8 = (u8*)(ws + (size_t)12582912);        // [4096][4096] fp8: 16,777,216
  u16* Mm   = (u16*)(ws + (size_t)29360128);       // [4096][3072] bf16: 25,165,824
  u16* wct  = (u16*)(ws + (size_t)54525952);       // 24 KB
  u16* lbt  = (u16*)(ws + (size_t)54550528);       // 24 KB
  float* outp = (float*)d_out;

  hipLaunchKernelGGL(kpre, dim3(5683), dim3(256), 0, stream,
                     adj, adj8, fcw, fcb, x, xht, Wz, Wr, Wh, Lz, Lr, Lh, wct, lbt);
  hipLaunchKernelGGL(k2, dim3(16, 32), dim3(256), 0, stream, adj8, xht, Mm);
  hipLaunchKernelGGL(k3, dim3(256), dim3(256), 0, stream, Mm, wct, lbt, bz, br, bh, outp);
}